// Round 19
// baseline (617.883 us; speedup 1.0000x reference)
//
#include <hip/hip_runtime.h>
#include <hip/hip_bf16.h>
#include <cstdint>
#include <cstddef>

typedef __attribute__((ext_vector_type(8))) short sh8;
typedef __attribute__((ext_vector_type(4))) short sh4;
typedef __attribute__((ext_vector_type(4))) int ix4;
typedef __attribute__((ext_vector_type(16))) float floatx16;
typedef unsigned short ushort_t;

__device__ __forceinline__ void glds16(const ushort_t* g, ushort_t* l) {
  __builtin_amdgcn_global_load_lds(
      (const __attribute__((address_space(1))) void*)g,
      (__attribute__((address_space(3))) void*)l, 16, 0, 0);
}

__device__ __forceinline__ ushort_t f2bf_bits(float f) {
  __hip_bfloat16 b = __float2bfloat16(f);
  return __builtin_bit_cast(unsigned short, b);
}
__device__ __forceinline__ float bf2f(ushort_t u) {
  unsigned int x = ((unsigned int)u) << 16;
  return __builtin_bit_cast(float, x);
}

// ---------------------------------------------------------------------------
// ELL build: ell[out*S + k] = in  (slot unique per (out,k) -> no atomics)
// ---------------------------------------------------------------------------
__global__ void build_ell_kernel(const int* __restrict__ in_idx,
                                 const int* __restrict__ out_idx,
                                 int K, int S, int P, int n_in, int n_out,
                                 int* __restrict__ ell) {
  int i = blockIdx.x * 256 + threadIdx.x;
  if (i >= K * P) return;
  int vin = in_idx[i];
  int vout = out_idx[i];
  if (vin < n_in && vout < n_out) {
    ell[(size_t)vout * S + (i / P)] = vin;
  }
}

// ---------------------------------------------------------------------------
// Weight pack into per-virtual-iter LDS image: Wp[vk][lc 0..7][co][8] bf16.
// ---------------------------------------------------------------------------
__global__ void pack_u_kernel(const float* __restrict__ W,
                              __hip_bfloat16* __restrict__ Wp,
                              int K, int CSPLIT, int COUT, long total) {
  long i = (long)blockIdx.x * 256 + threadIdx.x;
  if (i >= total) return;
  int co = (int)(i % COUT);
  long t = i / COUT;
  int vch = (int)(t % 64);
  int vk = (int)(t / 64);
  int k = vk / CSPLIT;
  int ci = (vk % CSPLIT) * 64 + vch;
  int CIN = CSPLIT * 64;
  float v = (k < K) ? W[((long)k * CIN + ci) * COUT + co] : 0.f;
  Wp[(((long)vk * 8 + (vch >> 3)) * COUT + co) * 8 + (vch & 7)] =
      __float2bfloat16(v);
}

// conv0 weights: W0[125][1][64] -> Wp0[k/16][co][k%16], k padded to 128.
__global__ void pack_w0_kernel(const float* __restrict__ W,
                               __hip_bfloat16* __restrict__ Wp) {
  int i = blockIdx.x * 256 + threadIdx.x;
  if (i >= 128 * 64) return;
  int co = i & 63;
  int ki = i >> 6;
  float v = (ki < 125) ? W[ki * 64 + co] : 0.f;
  Wp[(((ki >> 4) * 64) + co) * 16 + (ki & 15)] = __float2bfloat16(v);
}

// feats f32 -> bf16 with one zero pad element at the end.
__global__ void f2bf_kernel(const float* __restrict__ x,
                            __hip_bfloat16* __restrict__ y, long n, long npad) {
  long i = (long)blockIdx.x * 256 + threadIdx.x;
  if (i >= npad) return;
  y[i] = __float2bfloat16(i < n ? x[i] : 0.f);
}

// Fixed-order sum of P bf16 partial buffers -> bf16 final (deterministic).
__global__ void reduce_parts_kernel(const ushort_t* __restrict__ part, int P,
                                    long total, ushort_t* __restrict__ out) {
  long i = (long)blockIdx.x * 256 + threadIdx.x;
  if (i >= total) return;
  float s = 0.f;
  for (int p = 0; p < P; ++p) s += bf2f(part[(size_t)p * total + i]);
  out[i] = f2bf_bits(s);
}

// ---------------------------------------------------------------------------
// conv0: out[n0][64] (bf16) = gatherA(x1ch, ell[*,128]) @ W0, 32x32x16 MFMA.
// ---------------------------------------------------------------------------
__global__ __launch_bounds__(256, 2) void conv0_mfma_kernel(
    const ushort_t* __restrict__ xpad, const ushort_t* __restrict__ Wp0,
    const int* __restrict__ ell, int n_out, ushort_t* __restrict__ out) {
  constexpr int STR = 152;
  __shared__ ushort_t xs[64 * STR];
  const int tid = threadIdx.x;
  const int lane = tid & 63;
  const int wv = tid >> 6;
  const int wm = wv & 1, wn = wv >> 1;
  const long m0 = (long)blockIdx.x * 64;
  const int row = tid >> 2;
  const int kk0 = (tid & 3) * 32;
  const long grow = m0 + row;

  if (grow < n_out) {
    const ix4* ep = (const ix4*)(ell + grow * 128 + kk0);
#pragma unroll
    for (int g = 0; g < 8; ++g) {
      ix4 e = ep[g];
      sh4 v;
#pragma unroll
      for (int j = 0; j < 4; ++j) {
        int ix = (e[j] < 0) ? n_out : e[j];
        v[j] = (short)xpad[ix];
      }
      *(sh4*)(&xs[row * STR + kk0 + g * 4]) = v;
    }
  } else {
    sh4 z = (sh4)(short)0;
#pragma unroll
    for (int g = 0; g < 8; ++g) *(sh4*)(&xs[row * STR + kk0 + g * 4]) = z;
  }
  __syncthreads();

  const int arow = wm * 32 + (lane & 31);
  const int koff = (lane >> 5) * 8;
  const int bcol = wn * 32 + (lane & 31);
  floatx16 acc = (floatx16)(0.0f);
#pragma unroll
  for (int kc = 0; kc < 8; ++kc) {
    sh8 a = *(const sh8*)(&xs[arow * STR + kc * 16 + koff]);
    sh8 b = *(const sh8*)(Wp0 + ((size_t)kc * 64 + bcol) * 16 + koff);
    acc = __builtin_amdgcn_mfma_f32_32x32x16_bf16(a, b, acc, 0, 0, 0);
  }
  const int lrow = (lane >> 5) * 4;
#pragma unroll
  for (int r = 0; r < 16; ++r) {
    long orow = m0 + wm * 32 + (r & 3) + 8 * (r >> 2) + lrow;
    if (orow < n_out) out[orow * 64 + bcol] = f2bf_bits(acc[r]);
  }
}

// ---------------------------------------------------------------------------
// Unified MFMA implicit-GEMM conv, BM=128 x CT (128 for COUT>=128, else 64).
// BOTH A and B double-buffered (WAR distance = 2 barriers: proven safe in
// rounds 13-15; the single-buffered-B variant raced). Counted-vmcnt pipeline,
// 2 raw barriers/iter with lgkmcnt(0)+sched_barrier hardening before the
// WAR-side barrier. 1D grid + bijective chunked XCD swizzle; raw ell
// register-prefetch. Output always bf16 (finals or split-K partials).
// LDS: CT=128 -> 64KB (2 blocks/CU); CT=64 -> 48KB (3 blocks/CU).
// ---------------------------------------------------------------------------
template <int CSPLIT, int CT, bool HASELL>
__global__ __launch_bounds__(CT * 4, CT == 128 ? 4 : 3) void conv_u_kernel(
    const ushort_t* __restrict__ xb, const ushort_t* __restrict__ Wp,
    const int* __restrict__ ell, int S, int KI, int KP, int kdense,
    int n_out, int n_in, int COfull, int MB, int KS, int CS,
    ushort_t* __restrict__ out) {
  constexpr int BLK = CT * 4;
  constexpr int NWN = CT / 32;
  constexpr int ASEG_PW = 16 / (BLK / 64);        // 2 (CT=128) or 4 (CT=64)
  constexpr int BSEG_PW = (CT / 8) / (BLK / 64);  // 2
  constexpr int RW = CSPLIT * 64;
  __shared__ ushort_t Ab[2][128 * 64];
  __shared__ ushort_t Bb[2][8 * CT * 8];
  const int tid = threadIdx.x;
  const int lane = tid & 63;
  const int wv = tid >> 6;
  const int wm = wv / NWN, wn = wv % NWN;

  const int total = MB * KS * CS;
  const int l = blockIdx.x;
  const int q = total >> 3, r8 = total & 7;
  const int xcd = l & 7, pos = l >> 3;
  const int lp = (xcd < r8) ? (xcd * (q + 1) + pos)
                            : (r8 * (q + 1) + (xcd - r8) * q + pos);
  const int mblk = lp / (KS * CS);
  const int rem = lp - mblk * (KS * CS);
  const int yk = rem / CS;
  const int zc = rem - yk * CS;
  const long m0 = (long)mblk * 128;
  const int colbase = zc * CT;

  const int i0 = yk * KP;
  int cnt = KI - i0;
  if (cnt > KP) cnt = KP;
  out += (size_t)yk * ((size_t)n_out * COfull);

  floatx16 acc0 = (floatx16)(0.0f);
  floatx16 acc1 = (floatx16)(0.0f);

  auto loadEll = [&](int vk, int (&e)[ASEG_PW]) {
    if constexpr (HASELL) {
      const int kq = (CSPLIT == 1) ? vk : (vk / CSPLIT);
#pragma unroll
      for (int i = 0; i < ASEG_PW; ++i) {
        const int s = wv * ASEG_PW + i;
        const int r = s * 8 + (lane >> 3);
        long grow = m0 + r;
        long gc = grow < (long)(n_out - 1) ? grow : (long)(n_out - 1);
        e[i] = ell[gc * (long)S + kq];   // raw; masked at use
      }
    }
  };

  auto stage = [&](int vk, ushort_t* A, ushort_t* B, int (&eRaw)[ASEG_PW]) {
    const int sub = (CSPLIT == 1) ? 0 : (vk % CSPLIT);
    const int kq = (CSPLIT == 1) ? vk : (vk / CSPLIT);
#pragma unroll
    for (int i = 0; i < ASEG_PW; ++i) {
      const int s = wv * ASEG_PW + i;
      const int r = s * 8 + (lane >> 3);
      const long grow = m0 + r;
      int v;
      if constexpr (HASELL) v = eRaw[i];
      else v = (kq < kdense) ? (int)grow : -1;
      if (grow >= (long)n_out) v = -1;
      const int e = (v < 0) ? n_in : v;
      const int c = lane & 7;
      const int lc = c ^ (r & 7);
      glds16(xb + (size_t)e * RW + sub * 64 + lc * 8, A + s * 512 + lane * 8);
    }
    const ushort_t* wb = Wp + (size_t)vk * 8 * COfull * 8;
#pragma unroll
    for (int i = 0; i < BSEG_PW; ++i) {
      const int s = wv * BSEG_PW + i;
      int lc, co;
      if (CT == 128) { lc = s >> 1; co = (s & 1) * 64 + lane; }
      else           { lc = s;      co = lane; }
      glds16(wb + ((size_t)lc * COfull + colbase + co) * 8,
             B + s * 512 + lane * 8);
    }
  };
  auto compute = [&](const ushort_t* A, const ushort_t* B) {
    const int r0 = wm * 64 + (lane & 31);
    const int h = lane >> 5;
    const int co = wn * 32 + (lane & 31);
#pragma unroll
    for (int kc = 0; kc < 4; ++kc) {
      const int lc = kc * 2 + h;
      const int pc = lc ^ (r0 & 7);
      sh8 a0 = *(const sh8*)(A + r0 * 64 + pc * 8);
      sh8 a1 = *(const sh8*)(A + (r0 + 32) * 64 + pc * 8);
      sh8 b = *(const sh8*)(B + ((size_t)lc * CT + co) * 8);
      acc0 = __builtin_amdgcn_mfma_f32_32x32x16_bf16(a0, b, acc0, 0, 0, 0);
      acc1 = __builtin_amdgcn_mfma_f32_32x32x16_bf16(a1, b, acc1, 0, 0, 0);
    }
  };

  // steady-state vmcnt: newest outstanding = stage(j+1) glds + ell(j+2)
  constexpr int NWAIT = (ASEG_PW + BSEG_PW) + (HASELL ? ASEG_PW : 0);

  int eE[ASEG_PW] = {}, eO[ASEG_PW] = {};
  loadEll(i0, eE);
  stage(i0, Ab[0], Bb[0], eE);
  if (cnt > 1) loadEll(i0 + 1, eO);

#define CONV_ITER(J, P, SE, SO)                                                \
  if ((J) < cnt) {                                                             \
    __builtin_amdgcn_sched_barrier(0); /* pin compute(J-1) above */            \
    asm volatile("s_waitcnt lgkmcnt(0)" ::: "memory");                         \
    __builtin_amdgcn_s_barrier(); /* compute(J-1) done: bufs P^1 free */       \
    if ((J) + 1 < cnt) {                                                       \
      stage(i0 + (J) + 1, Ab[(P) ^ 1], Bb[(P) ^ 1], SO);                       \
      if ((J) + 2 < cnt) loadEll(i0 + (J) + 2, SE);                            \
      if constexpr (NWAIT == 4)                                                \
        asm volatile("s_waitcnt vmcnt(4)" ::: "memory");                       \
      else if constexpr (NWAIT == 6)                                           \
        asm volatile("s_waitcnt vmcnt(6)" ::: "memory");                       \
      else                                                                     \
        asm volatile("s_waitcnt vmcnt(10)" ::: "memory");                      \
    } else {                                                                   \
      asm volatile("s_waitcnt vmcnt(0)" ::: "memory");                         \
    }                                                                          \
    __builtin_amdgcn_s_barrier(); /* stage(J) visible to all waves */          \
    __builtin_amdgcn_sched_barrier(0);                                         \
    compute(Ab[P], Bb[P]);                                                     \
  }

  for (int j = 0; j < cnt; j += 2) {
    CONV_ITER(j, 0, eE, eO)
    CONV_ITER(j + 1, 1, eO, eE)
  }
#undef CONV_ITER

  const int ccol = colbase + wn * 32 + (lane & 31);
  const int rb = wm * 64 + (lane >> 5) * 4;
#pragma unroll
  for (int rr = 0; rr < 16; ++rr) {
    long row = m0 + rb + (rr & 3) + 8 * (rr >> 2);
    if (row < n_out) out[row * COfull + ccol] = f2bf_bits(acc0[rr]);
    long row1 = row + 32;
    if (row1 < n_out) out[row1 * COfull + ccol] = f2bf_bits(acc1[rr]);
  }
}

// ---------------------------------------------------------------------------
// BN over bf16 conv outputs: two-pass stats + fused apply (res/ReLU/outs).
// ---------------------------------------------------------------------------
template <int C>
__global__ void bn_reduce1_kernel(const ushort_t* __restrict__ x, int n,
                                  float* __restrict__ part) {
  constexpr int C4 = C / 4;
  constexpr int RL = 256 / C4;
  const int c4 = threadIdx.x % C4;
  const int rl = threadIdx.x / C4;
  float4 s = {0.f, 0.f, 0.f, 0.f}, ss = {0.f, 0.f, 0.f, 0.f};
  for (long row = (long)blockIdx.x * RL + rl; row < n;
       row += (long)gridDim.x * RL) {
    ushort4 u = *(const ushort4*)(x + row * C + c4 * 4);
    float v0 = bf2f(u.x), v1 = bf2f(u.y), v2 = bf2f(u.z), v3 = bf2f(u.w);
    s.x += v0; s.y += v1; s.z += v2; s.w += v3;
    ss.x += v0 * v0; ss.y += v1 * v1; ss.z += v2 * v2; ss.w += v3 * v3;
  }
  __shared__ float4 sh[512];
  sh[threadIdx.x] = s;
  sh[256 + threadIdx.x] = ss;
  __syncthreads();
  if (rl == 0) {
#pragma unroll
    for (int j = 1; j < RL; ++j) {
      float4 a = sh[j * C4 + c4];
      float4 b = sh[256 + j * C4 + c4];
      s.x += a.x; s.y += a.y; s.z += a.z; s.w += a.w;
      ss.x += b.x; ss.y += b.y; ss.z += b.z; ss.w += b.w;
    }
    *(float4*)(part + (size_t)blockIdx.x * 2 * C + c4 * 4) = s;
    *(float4*)(part + (size_t)blockIdx.x * 2 * C + C + c4 * 4) = ss;
  }
}

// Parallel stats reduce: grid = C blocks x 256 threads (fixed-order tree).
template <int C>
__global__ void bn_reduce2_kernel(const float* __restrict__ part, int G,
                                  float* __restrict__ stats) {
  const int c = blockIdx.x;
  const int g = threadIdx.x;
  __shared__ float sh[512];
  float s = 0.f, ss = 0.f;
  if (g < G) {
    s = part[(size_t)g * 2 * C + c];
    ss = part[(size_t)g * 2 * C + C + c];
  }
  sh[g] = s;
  sh[256 + g] = ss;
  __syncthreads();
#pragma unroll
  for (int off = 128; off > 0; off >>= 1) {
    if (g < off) {
      sh[g] += sh[g + off];
      sh[256 + g] += sh[256 + g + off];
    }
    __syncthreads();
  }
  if (g == 0) {
    stats[c] = sh[0];
    stats[C + c] = sh[256];
  }
}

// Vectorized apply: one float4-worth (4 channels) per thread per step.
template <int C, bool RELU, bool RES, bool WF32>
__global__ void bn_apply_kernel(const ushort_t* __restrict__ x,
                                const float* __restrict__ stats,
                                const float* __restrict__ gamma,
                                const float* __restrict__ beta,
                                const float* __restrict__ res,
                                long total4, float inv_n,
                                float* __restrict__ out,
                                ushort_t* __restrict__ outb, long padEnd4) {
  constexpr int C4 = C / 4;
  for (long i = (long)blockIdx.x * 256 + threadIdx.x; i < padEnd4;
       i += (long)gridDim.x * 256) {
    if (i >= total4) {
      if (outb) *(ushort4*)(outb + i * 4) = (ushort4){0, 0, 0, 0};
      continue;
    }
    const int c4 = (int)(i % C4);
    float4 sum = *(const float4*)(stats + c4 * 4);
    float4 sq = *(const float4*)(stats + C + c4 * 4);
    float4 g4 = *(const float4*)(gamma + c4 * 4);
    float4 b4 = *(const float4*)(beta + c4 * 4);
    ushort4 u = *(const ushort4*)(x + i * 4);
    float vin[4] = {bf2f(u.x), bf2f(u.y), bf2f(u.z), bf2f(u.w)};
    float4 r4 = {0.f, 0.f, 0.f, 0.f};
    if (RES) r4 = *(const float4*)(res + i * 4);
    float o[4];
#pragma unroll
    for (int j = 0; j < 4; ++j) {
      float m = ((const float*)&sum)[j] * inv_n;
      float var = ((const float*)&sq)[j] * inv_n - m * m;
      float sc = rsqrtf(var + 1e-5f) * ((const float*)&g4)[j];
      float val = (vin[j] - m) * sc + ((const float*)&b4)[j];
      if (RES) val += ((const float*)&r4)[j];
      if (RELU) val = fmaxf(val, 0.f);
      o[j] = val;
    }
    if (WF32) *(float4*)(out + i * 4) = (float4){o[0], o[1], o[2], o[3]};
    if (outb) {
      ushort4 w = {f2bf_bits(o[0]), f2bf_bits(o[1]), f2bf_bits(o[2]),
                   f2bf_bits(o[3])};
      *(ushort4*)(outb + i * 4) = w;
    }
  }
}

// ---------------------------------------------------------------------------

extern "C" void kernel_launch(void* const* d_in, const int* in_sizes, int n_in,
                              void* d_out, int out_size, void* d_ws,
                              size_t ws_size, hipStream_t stream) {
  const float* feats = (const float*)d_in[0];
  const float* W0  = (const float*)d_in[1];
  const float* g0  = (const float*)d_in[2];
  const float* b0  = (const float*)d_in[3];
  const float* Ws1 = (const float*)d_in[4];
  const float* gs1 = (const float*)d_in[5];
  const float* bs1 = (const float*)d_in[6];
  const float* Wa1 = (const float*)d_in[7];
  const float* ga1 = (const float*)d_in[8];
  const float* ba1 = (const float*)d_in[9];
  const float* Wb1 = (const float*)d_in[10];
  const float* gb1 = (const float*)d_in[11];
  const float* bb1 = (const float*)d_in[12];
  const float* Ws2 = (const float*)d_in[13];
  const float* gs2 = (const float*)d_in[14];
  const float* bs2 = (const float*)d_in[15];
  const float* Wa2 = (const float*)d_in[16];
  const float* ga2 = (const float*)d_in[17];
  const float* ba2 = (const float*)d_in[18];
  const float* Wb2 = (const float*)d_in[19];
  const float* gb2 = (const float*)d_in[20];
  const float* bb2 = (const float*)d_in[21];
  const float* Wd2 = (const float*)d_in[22];
  const float* gd2 = (const float*)d_in[23];
  const float* bd2 = (const float*)d_in[24];
  const float* Ws3 = (const float*)d_in[25];
  const float* gs3 = (const float*)d_in[26];
  const float* bs3 = (const float*)d_in[27];
  const float* Wa3 = (const float*)d_in[28];
  const float* ga3 = (const float*)d_in[29];
  const float* ba3 = (const float*)d_in[30];
  const float* Wb3 = (const float*)d_in[31];
  const float* gb3 = (const float*)d_in[32];
  const float* bb3 = (const float*)d_in[33];
  const float* Wd3 = (const float*)d_in[34];
  const float* gd3 = (const float*)d_in[35];
  const float* bd3 = (const float*)d_in[36];
  const int* im0  = (const int*)d_in[40];
  const int* om0  = (const int*)d_in[41];
  const int* ims1 = (const int*)d_in[42];
  const int* oms1 = (const int*)d_in[43];
  const int* imb1 = (const int*)d_in[44];
  const int* omb1 = (const int*)d_in[45];
  const int* ims2 = (const int*)d_in[46];
  const int* oms2 = (const int*)d_in[47];
  const int* imb2 = (const int*)d_in[48];
  const int* omb2 = (const int*)d_in[49];
  const int* ims3 = (const int*)d_in[50];
  const int* oms3 = (const int*)d_in[51];
  const int* imb3 = (const int*)d_in[52];
  const int* omb3 = (const int*)d_in[53];

  const int n0 = in_sizes[0];
  const int n1 = in_sizes[37] / 3;
  const int n2 = in_sizes[38] / 3;
  const int n3 = in_sizes[39] / 3;
  const int P0  = in_sizes[40] / 125;
  const int Ps1 = in_sizes[42] / 8;
  const int Pb1 = in_sizes[44] / 27;
  const int Ps2 = in_sizes[46] / 8;
  const int Pb2 = in_sizes[48] / 27;
  const int Ps3 = in_sizes[50] / 8;
  const int Pb3 = in_sizes[52] / 27;

  // ---- workspace carve ----
  char* w = (char*)d_ws;
  auto carve = [&](size_t bytes) {
    char* p = w;
    w += (bytes + 255) & ~(size_t)255;
    return p;
  };
  int* ellS = (int*)carve((size_t)n0 * 128 * sizeof(int));
  int* ellB = (int*)carve((size_t)n1 * 28 * sizeof(int));
  float* part = (float*)carve((size_t)256 * 512 * sizeof(float));
  float* stats = (float*)carve((size_t)512 * sizeof(float));
  size_t capE = (size_t)n0 * 64 + 512;  // + pad row
  float* buf1 = (float*)carve(capE * sizeof(float));        // residual f32
  float* buf2 = (float*)carve(capE * sizeof(float));        // residual f32
  __hip_bfloat16* bbA = (__hip_bfloat16*)carve(capE * 2);   // BN bf16 outs
  __hip_bfloat16* bbB = (__hip_bfloat16*)carve(capE * 2);
  __hip_bfloat16* bbC = (__hip_bfloat16*)carve(capE * 2);
  ushort_t* cb1 = (ushort_t*)carve(capE * 2);               // conv bf16 outs
  ushort_t* cb2 = (ushort_t*)carve(capE * 2);
  ushort_t* cb3 = (ushort_t*)carve(capE * 2);
  __hip_bfloat16* xfeat = (__hip_bfloat16*)carve(((size_t)n0 + 1) * 2);

  // ---- weight packing into LDS-image layout ----
  auto packu = [&](const float* W, int K, int cin, int cout) {
    int csplit = cin / 64;
    long tot = (long)K * csplit * 64 * cout;
    __hip_bfloat16* Wp = (__hip_bfloat16*)carve((size_t)tot * 2);
    pack_u_kernel<<<(int)((tot + 255) / 256), 256, 0, stream>>>(
        W, Wp, K, csplit, cout, tot);
    return Wp;
  };
  __hip_bfloat16* Wp0 = (__hip_bfloat16*)carve((size_t)128 * 64 * 2);
  pack_w0_kernel<<<32, 256, 0, stream>>>(W0, Wp0);
  __hip_bfloat16* Ps1p = packu(Ws1, 8, 64, 64);
  __hip_bfloat16* Pa1p = packu(Wa1, 27, 64, 64);
  __hip_bfloat16* Pb1p = packu(Wb1, 27, 64, 64);
  __hip_bfloat16* Ps2p = packu(Ws2, 8, 64, 64);
  __hip_bfloat16* Pd2p = packu(Wd2, 1, 64, 128);
  __hip_bfloat16* Pa2p = packu(Wa2, 27, 64, 128);
  __hip_bfloat16* Pb2p = packu(Wb2, 27, 128, 128);
  __hip_bfloat16* Ps3p = packu(Ws3, 8, 128, 128);
  __hip_bfloat16* Pd3p = packu(Wd3, 1, 128, 256);
  __hip_bfloat16* Pa3p = packu(Wa3, 27, 128, 256);
  __hip_bfloat16* Pb3p = packu(Wb3, 27, 256, 256);

  // split-K partial buffer (bf16): all remaining workspace
  size_t used = (size_t)(w - (char*)d_ws);
  ushort_t* pbufU = (ushort_t*)w;
  size_t pcapU = (ws_size > used) ? (ws_size - used) / 2 : 0;

  f2bf_kernel<<<(int)((n0 + 256) / 256), 256, 0, stream>>>(feats, xfeat, n0,
                                                           n0 + 1);

  auto buildEll = [&](int* ellbuf, const int* im, const int* om, int K, int S,
                      int P, int nin, int nout) {
    hipMemsetAsync(ellbuf, 0xFF, (size_t)nout * S * sizeof(int), stream);
    int tot = K * P;
    build_ell_kernel<<<(tot + 255) / 256, 256, 0, stream>>>(im, om, K, S, P,
                                                            nin, nout, ellbuf);
  };

  auto convu = [&](const __hip_bfloat16* xb, const __hip_bfloat16* Wp,
                   const int* ellp, int S, int K, int kdense, int nout,
                   int nin, int cin, int cout, ushort_t* outc) {
    int csplit = cin / 64;
    int KIv = K * csplit;
    int CT = (cout >= 128) ? 128 : 64;   // round-13 policy
    int cs = cout / CT;
    int mb = (nout + 127) / 128;
    int tiles = mb * cs;
    int ks = 1;
    if (tiles < 512 && KIv > 1) {
      ks = (512 + tiles - 1) / tiles;
      if (ks > 8) ks = 8;
      if (ks > KIv) ks = KIv;
      size_t need = (size_t)nout * cout;
      int fit = need ? (int)(pcapU / need) : 1;
      if (ks > fit) ks = fit;
      if (ks < 1) ks = 1;
    }
    int KP = (KIv + ks - 1) / ks;
    int ksE = (KIv + KP - 1) / KP;
    ushort_t* tgt = (ksE > 1) ? pbufU : outc;
    int gridx = mb * ksE * cs;
#define CU_CASE(CSV, CTV)                                                      \
  else if (csplit == CSV && CT == CTV) {                                       \
    if (ellp)                                                                  \
      conv_u_kernel<CSV, CTV, true><<<gridx, CTV * 4, 0, stream>>>(            \
          (const ushort_t*)xb, (const ushort_t*)Wp, ellp, S, KIv, KP, kdense,  \
          nout, nin, cout, mb, ksE, cs, tgt);                                  \
    else                                                                       \
      conv_u_kernel<CSV, CTV, false><<<gridx, CTV * 4, 0, stream>>>(           \
          (const ushort_t*)xb, (const ushort_t*)Wp, ellp, S, KIv, KP, kdense,  \
          nout, nin, cout, mb, ksE, cs, tgt);                                  \
  }
    if (false) {}
    CU_CASE(1, 64)
    CU_CASE(1, 128)
    CU_CASE(2, 128)
    CU_CASE(4, 128)
#undef CU_CASE
    if (ksE > 1) {
      long total = (long)nout * cout;
      reduce_parts_kernel<<<(int)((total + 255) / 256), 256, 0, stream>>>(
          pbufU, ksE, total, outc);
    }
  };

  auto bn = [&](const ushort_t* x, int n, int C, const float* gamma,
                const float* beta, const float* res, bool relu, float* outp,
                __hip_bfloat16* outb) {
    const int G = 256;
    float invn = 1.0f / (float)n;
    long total4 = (long)n * C / 4;
    long padEnd4 = outb ? (total4 + C / 4) : total4;
    int agrid = (int)((padEnd4 + 255) / 256);
    if (agrid > 2048) agrid = 2048;
    ushort_t* outbu = (ushort_t*)outb;
#define BN_CASE(CC)                                                            \
  else if (C == CC) {                                                          \
    bn_reduce1_kernel<CC><<<G, 256, 0, stream>>>(x, n, part);                  \
    bn_reduce2_kernel<CC><<<CC, 256, 0, stream>>>(part, G, stats);             \
    if (res && relu)                                                           \
      bn_apply_kernel<CC, true, true, true><<<agrid, 256, 0, stream>>>(        \
          x, stats, gamma, beta, res, total4, invn, outp, outbu, padEnd4);     \
    else if (relu && outp)                                                     \
      bn_apply_kernel<CC, true, false, true><<<agrid, 256, 0, stream>>>(       \
          x, stats, gamma, beta, nullptr, total4, invn, outp, outbu,           \
          padEnd4);                                                            \
    else if (relu)                                                             \
      bn_apply_kernel<CC, true, false, false><<<agrid, 256, 0, stream>>>(      \
          x, stats, gamma, beta, nullptr, total4, invn, nullptr, outbu,        \
          padEnd4);                                                            \
    else                                                                       \
      bn_apply_kernel<CC, false, false, true><<<agrid, 256, 0, stream>>>(      \
          x, stats, gamma, beta, nullptr, total4, invn, outp, outbu,           \
          padEnd4);                                                            \
  }
    if (false) {}
    BN_CASE(64)
    BN_CASE(128)
    BN_CASE(256)
#undef BN_CASE
  };

  float* y1 = (float*)d_out;
  float* y2 = y1 + (size_t)n1 * 64;
  float* y3 = y2 + (size_t)n2 * 128;

  // ---- stem: conv0 (k=125 -> GEMM over K=128, bf16 out) + BN ----
  buildEll(ellS, im0, om0, 125, 128, P0, n0, n0);
  conv0_mfma_kernel<<<(n0 + 63) / 64, 256, 0, stream>>>(
      (const ushort_t*)xfeat, (const ushort_t*)Wp0, ellS, n0, cb1);
  bn(cb1, n0, 64, g0, b0, nullptr, true, nullptr, bbA);             // x0

  // ---- level 1 ----
  buildEll(ellS, ims1, oms1, 8, 8, Ps1, n0, n1);
  convu(bbA, Ps1p, ellS, 8, 8, 0, n1, n0, 64, 64, cb2);
  bn(cb2, n1, 64, gs1, bs1, nullptr, true, buf2, bbB);              // x1
  buildEll(ellB, imb1, omb1, 27, 28, Pb1, n1, n1);
  convu(bbB, Pa1p, ellB, 28, 27, 0, n1, n1, 64, 64, cb3);
  bn(cb3, n1, 64, ga1, ba1, nullptr, true, nullptr, bbC);           // h1a
  convu(bbC, Pb1p, ellB, 28, 27, 0, n1, n1, 64, 64, cb1);
  bn(cb1, n1, 64, gb1, bb1, buf2, true, y1, bbA);                   // y1

  // ---- level 2 ----
  buildEll(ellS, ims2, oms2, 8, 8, Ps2, n1, n2);
  convu(bbA, Ps2p, ellS, 8, 8, 0, n2, n1, 64, 64, cb2);
  bn(cb2, n2, 64, gs2, bs2, nullptr, true, nullptr, bbB);           // x2
  convu(bbB, Pd2p, nullptr, 1, 1, 1, n2, n2, 64, 128, cb3);
  bn(cb3, n2, 128, gd2, bd2, nullptr, false, buf1, nullptr);        // res2
  buildEll(ellB, imb2, omb2, 27, 28, Pb2, n2, n2);
  convu(bbB, Pa2p, ellB, 28, 27, 0, n2, n2, 64, 128, cb2);
  bn(cb2, n2, 128, ga2, ba2, nullptr, true, nullptr, bbC);          // h2a
  convu(bbC, Pb2p, ellB, 28, 27, 0, n2, n2, 128, 128, cb3);
  bn(cb3, n2, 128, gb2, bb2, buf1, true, y2, bbA);                  // y2

  // ---- level 3 ----
  buildEll(ellS, ims3, oms3, 8, 8, Ps3, n2, n3);
  convu(bbA, Ps3p, ellS, 8, 8, 0, n3, n2, 128, 128, cb1);
  bn(cb1, n3, 128, gs3, bs3, nullptr, true, nullptr, bbB);          // x3
  convu(bbB, Pd3p, nullptr, 1, 1, 1, n3, n3, 128, 256, cb2);
  bn(cb2, n3, 256, gd3, bd3, nullptr, false, buf2, nullptr);        // res3
  buildEll(ellB, imb3, omb3, 27, 28, Pb3, n3, n3);
  convu(bbB, Pa3p, ellB, 28, 27, 0, n3, n3, 128, 256, cb1);
  bn(cb1, n3, 256, ga3, ba3, nullptr, true, nullptr, bbC);          // h3a
  convu(bbC, Pb3p, ellB, 28, 27, 0, n3, n3, 256, 256, cb2);
  bn(cb2, n3, 256, gb3, bb3, buf2, true, y3, nullptr);              // y3
}

// Round 20
// 599.798 us; speedup vs baseline: 1.0302x; 1.0302x over previous
//
#include <hip/hip_runtime.h>
#include <hip/hip_bf16.h>
#include <cstdint>
#include <cstddef>

typedef __attribute__((ext_vector_type(8))) short sh8;
typedef __attribute__((ext_vector_type(4))) short sh4;
typedef __attribute__((ext_vector_type(4))) int ix4;
typedef __attribute__((ext_vector_type(16))) float floatx16;
typedef unsigned short ushort_t;

__device__ __forceinline__ void glds16(const ushort_t* g, ushort_t* l) {
  __builtin_amdgcn_global_load_lds(
      (const __attribute__((address_space(1))) void*)g,
      (__attribute__((address_space(3))) void*)l, 16, 0, 0);
}

__device__ __forceinline__ ushort_t f2bf_bits(float f) {
  __hip_bfloat16 b = __float2bfloat16(f);
  return __builtin_bit_cast(unsigned short, b);
}
__device__ __forceinline__ float bf2f(ushort_t u) {
  unsigned int x = ((unsigned int)u) << 16;
  return __builtin_bit_cast(float, x);
}

// ---------------------------------------------------------------------------
// ELL init/build. ell[out*S + k] = in (slot unique per (out,k) -> no atomics)
// Dual-table variants cover a whole level in 2 dispatches.
// ---------------------------------------------------------------------------
__global__ void init_ell2_kernel(int* __restrict__ e1, long sz1,
                                 int* __restrict__ e2, long sz2) {
  long i = (long)blockIdx.x * 256 + threadIdx.x;
  if (i < sz1) e1[i] = -1;
  else if (i < sz1 + sz2) e2[i - sz1] = -1;
}

__global__ void build_ell2_kernel(
    const int* __restrict__ i1, const int* __restrict__ o1, int K1, int S1,
    int P1, int nin1, int nout1, int* __restrict__ e1,
    const int* __restrict__ i2, const int* __restrict__ o2, int K2, int S2,
    int P2, int nin2, int nout2, int* __restrict__ e2) {
  long i = (long)blockIdx.x * 256 + threadIdx.x;
  long t1 = (long)K1 * P1;
  if (i < t1) {
    int vin = i1[i], vout = o1[i];
    if (vin < nin1 && vout < nout1) e1[(size_t)vout * S1 + (i / P1)] = vin;
  } else if (i < t1 + (long)K2 * P2) {
    long j = i - t1;
    int vin = i2[j], vout = o2[j];
    if (vin < nin2 && vout < nout2) e2[(size_t)vout * S2 + (j / P2)] = vin;
  }
}

__global__ void build_ell_kernel(const int* __restrict__ in_idx,
                                 const int* __restrict__ out_idx,
                                 int K, int S, int P, int n_in, int n_out,
                                 int* __restrict__ ell) {
  int i = blockIdx.x * 256 + threadIdx.x;
  if (i >= K * P) return;
  int vin = in_idx[i];
  int vout = out_idx[i];
  if (vin < n_in && vout < n_out) {
    ell[(size_t)vout * S + (i / P)] = vin;
  }
}

// ---------------------------------------------------------------------------
// Batched weight pack: 11 weights in ONE dispatch.
// Layout per weight: Wp[vk][lc 0..7][co][8] bf16 (vk = K*CSPLIT virtual iters)
// ---------------------------------------------------------------------------
struct PackDesc {
  const float* W;
  ushort_t* Wp;
  int K, CSPLIT, COUT, pad;
};
struct PackAll {
  PackDesc d[11];
  long cum[12];
};

__global__ void pack_all_kernel(PackAll pa, long grand) {
  long i = (long)blockIdx.x * 256 + threadIdx.x;
  if (i >= grand) return;
  int di = 0;
#pragma unroll
  for (int s = 0; s < 11; ++s)
    if (i >= pa.cum[s + 1]) di = s + 1;
  const PackDesc& D = pa.d[di];
  long j = i - pa.cum[di];
  int co = (int)(j % D.COUT);
  long t = j / D.COUT;
  int vch = (int)(t % 64);
  int vk = (int)(t / 64);
  int k = vk / D.CSPLIT;
  int ci = (vk % D.CSPLIT) * 64 + vch;
  int CIN = D.CSPLIT * 64;
  float v = (k < D.K) ? D.W[((long)k * CIN + ci) * D.COUT + co] : 0.f;
  D.Wp[(((long)vk * 8 + (vch >> 3)) * D.COUT + co) * 8 + (vch & 7)] =
      f2bf_bits(v);
}

// conv0 weights: W0[125][1][64] -> Wp0[k/16][co][k%16], k padded to 128.
__global__ void pack_w0_kernel(const float* __restrict__ W,
                               __hip_bfloat16* __restrict__ Wp) {
  int i = blockIdx.x * 256 + threadIdx.x;
  if (i >= 128 * 64) return;
  int co = i & 63;
  int ki = i >> 6;
  float v = (ki < 125) ? W[ki * 64 + co] : 0.f;
  Wp[(((ki >> 4) * 64) + co) * 16 + (ki & 15)] = __float2bfloat16(v);
}

// feats f32 -> bf16 with one zero pad element at the end.
__global__ void f2bf_kernel(const float* __restrict__ x,
                            __hip_bfloat16* __restrict__ y, long n, long npad) {
  long i = (long)blockIdx.x * 256 + threadIdx.x;
  if (i >= npad) return;
  y[i] = __float2bfloat16(i < n ? x[i] : 0.f);
}

// Plain fixed-order reduce (kept for completeness; unused when stats fused).
__global__ void reduce_parts_kernel(const ushort_t* __restrict__ part, int P,
                                    long total, ushort_t* __restrict__ out) {
  long i = (long)blockIdx.x * 256 + threadIdx.x;
  if (i >= total) return;
  float s = 0.f;
  for (int p = 0; p < P; ++p) s += bf2f(part[(size_t)p * total + i]);
  out[i] = f2bf_bits(s);
}

// ---------------------------------------------------------------------------
// Fixed-order sum of P bf16 partials -> bf16 final + per-block BN-stat
// partials of the ROUNDED finals. Same 256-block / RL / loop order as
// bn_reduce1 -> stats are bit-identical to the two-pass version.
// ---------------------------------------------------------------------------
template <int C>
__global__ void reduce_parts_stats_kernel(const ushort_t* __restrict__ pin,
                                          int P, int n,
                                          ushort_t* __restrict__ out,
                                          float* __restrict__ part) {
  constexpr int C4 = C / 4;
  constexpr int RL = 256 / C4;
  const long total = (long)n * C;
  const int c4 = threadIdx.x % C4;
  const int rl = threadIdx.x / C4;
  float4 s = {0.f, 0.f, 0.f, 0.f}, ss = {0.f, 0.f, 0.f, 0.f};
  for (long row = (long)blockIdx.x * RL + rl; row < n;
       row += (long)gridDim.x * RL) {
    long base = row * C + c4 * 4;
    float f0 = 0.f, f1 = 0.f, f2 = 0.f, f3 = 0.f;
    for (int p = 0; p < P; ++p) {
      ushort4 u = *(const ushort4*)(pin + (size_t)p * total + base);
      f0 += bf2f(u.x); f1 += bf2f(u.y); f2 += bf2f(u.z); f3 += bf2f(u.w);
    }
    ushort4 w = {f2bf_bits(f0), f2bf_bits(f1), f2bf_bits(f2), f2bf_bits(f3)};
    *(ushort4*)(out + base) = w;
    float v0 = bf2f(w.x), v1 = bf2f(w.y), v2 = bf2f(w.z), v3 = bf2f(w.w);
    s.x += v0; s.y += v1; s.z += v2; s.w += v3;
    ss.x += v0 * v0; ss.y += v1 * v1; ss.z += v2 * v2; ss.w += v3 * v3;
  }
  __shared__ float4 sh[512];
  sh[threadIdx.x] = s;
  sh[256 + threadIdx.x] = ss;
  __syncthreads();
  if (rl == 0) {
#pragma unroll
    for (int j = 1; j < RL; ++j) {
      float4 a = sh[j * C4 + c4];
      float4 b = sh[256 + j * C4 + c4];
      s.x += a.x; s.y += a.y; s.z += a.z; s.w += a.w;
      ss.x += b.x; ss.y += b.y; ss.z += b.z; ss.w += b.w;
    }
    *(float4*)(part + (size_t)blockIdx.x * 2 * C + c4 * 4) = s;
    *(float4*)(part + (size_t)blockIdx.x * 2 * C + C + c4 * 4) = ss;
  }
}

// ---------------------------------------------------------------------------
// conv0: out[n0][64] (bf16) = gatherA(x1ch, ell[*,128]) @ W0, 32x32x16 MFMA.
// ---------------------------------------------------------------------------
__global__ __launch_bounds__(256, 2) void conv0_mfma_kernel(
    const ushort_t* __restrict__ xpad, const ushort_t* __restrict__ Wp0,
    const int* __restrict__ ell, int n_out, ushort_t* __restrict__ out) {
  constexpr int STR = 152;
  __shared__ ushort_t xs[64 * STR];
  const int tid = threadIdx.x;
  const int lane = tid & 63;
  const int wv = tid >> 6;
  const int wm = wv & 1, wn = wv >> 1;
  const long m0 = (long)blockIdx.x * 64;
  const int row = tid >> 2;
  const int kk0 = (tid & 3) * 32;
  const long grow = m0 + row;

  if (grow < n_out) {
    const ix4* ep = (const ix4*)(ell + grow * 128 + kk0);
#pragma unroll
    for (int g = 0; g < 8; ++g) {
      ix4 e = ep[g];
      sh4 v;
#pragma unroll
      for (int j = 0; j < 4; ++j) {
        int ix = (e[j] < 0) ? n_out : e[j];
        v[j] = (short)xpad[ix];
      }
      *(sh4*)(&xs[row * STR + kk0 + g * 4]) = v;
    }
  } else {
    sh4 z = (sh4)(short)0;
#pragma unroll
    for (int g = 0; g < 8; ++g) *(sh4*)(&xs[row * STR + kk0 + g * 4]) = z;
  }
  __syncthreads();

  const int arow = wm * 32 + (lane & 31);
  const int koff = (lane >> 5) * 8;
  const int bcol = wn * 32 + (lane & 31);
  floatx16 acc = (floatx16)(0.0f);
#pragma unroll
  for (int kc = 0; kc < 8; ++kc) {
    sh8 a = *(const sh8*)(&xs[arow * STR + kc * 16 + koff]);
    sh8 b = *(const sh8*)(Wp0 + ((size_t)kc * 64 + bcol) * 16 + koff);
    acc = __builtin_amdgcn_mfma_f32_32x32x16_bf16(a, b, acc, 0, 0, 0);
  }
  const int lrow = (lane >> 5) * 4;
#pragma unroll
  for (int r = 0; r < 16; ++r) {
    long orow = m0 + wm * 32 + (r & 3) + 8 * (r >> 2) + lrow;
    if (orow < n_out) out[orow * 64 + bcol] = f2bf_bits(acc[r]);
  }
}

// ---------------------------------------------------------------------------
// Unified MFMA implicit-GEMM conv (UNCHANGED from round 19 — proven safe).
// BM=128 x CT; A+B double-buffered (WAR distance = 2 barriers), counted
// vmcnt, lgkmcnt(0)+sched_barrier hardening. bf16 outputs.
// ---------------------------------------------------------------------------
template <int CSPLIT, int CT, bool HASELL>
__global__ __launch_bounds__(CT * 4, CT == 128 ? 4 : 3) void conv_u_kernel(
    const ushort_t* __restrict__ xb, const ushort_t* __restrict__ Wp,
    const int* __restrict__ ell, int S, int KI, int KP, int kdense,
    int n_out, int n_in, int COfull, int MB, int KS, int CS,
    ushort_t* __restrict__ out) {
  constexpr int BLK = CT * 4;
  constexpr int NWN = CT / 32;
  constexpr int ASEG_PW = 16 / (BLK / 64);        // 2 (CT=128) or 4 (CT=64)
  constexpr int BSEG_PW = (CT / 8) / (BLK / 64);  // 2
  constexpr int RW = CSPLIT * 64;
  __shared__ ushort_t Ab[2][128 * 64];
  __shared__ ushort_t Bb[2][8 * CT * 8];
  const int tid = threadIdx.x;
  const int lane = tid & 63;
  const int wv = tid >> 6;
  const int wm = wv / NWN, wn = wv % NWN;

  const int total = MB * KS * CS;
  const int l = blockIdx.x;
  const int q = total >> 3, r8 = total & 7;
  const int xcd = l & 7, pos = l >> 3;
  const int lp = (xcd < r8) ? (xcd * (q + 1) + pos)
                            : (r8 * (q + 1) + (xcd - r8) * q + pos);
  const int mblk = lp / (KS * CS);
  const int rem = lp - mblk * (KS * CS);
  const int yk = rem / CS;
  const int zc = rem - yk * CS;
  const long m0 = (long)mblk * 128;
  const int colbase = zc * CT;

  const int i0 = yk * KP;
  int cnt = KI - i0;
  if (cnt > KP) cnt = KP;
  out += (size_t)yk * ((size_t)n_out * COfull);

  floatx16 acc0 = (floatx16)(0.0f);
  floatx16 acc1 = (floatx16)(0.0f);

  auto loadEll = [&](int vk, int (&e)[ASEG_PW]) {
    if constexpr (HASELL) {
      const int kq = (CSPLIT == 1) ? vk : (vk / CSPLIT);
#pragma unroll
      for (int i = 0; i < ASEG_PW; ++i) {
        const int s = wv * ASEG_PW + i;
        const int r = s * 8 + (lane >> 3);
        long grow = m0 + r;
        long gc = grow < (long)(n_out - 1) ? grow : (long)(n_out - 1);
        e[i] = ell[gc * (long)S + kq];   // raw; masked at use
      }
    }
  };

  auto stage = [&](int vk, ushort_t* A, ushort_t* B, int (&eRaw)[ASEG_PW]) {
    const int sub = (CSPLIT == 1) ? 0 : (vk % CSPLIT);
    const int kq = (CSPLIT == 1) ? vk : (vk / CSPLIT);
#pragma unroll
    for (int i = 0; i < ASEG_PW; ++i) {
      const int s = wv * ASEG_PW + i;
      const int r = s * 8 + (lane >> 3);
      const long grow = m0 + r;
      int v;
      if constexpr (HASELL) v = eRaw[i];
      else v = (kq < kdense) ? (int)grow : -1;
      if (grow >= (long)n_out) v = -1;
      const int e = (v < 0) ? n_in : v;
      const int c = lane & 7;
      const int lc = c ^ (r & 7);
      glds16(xb + (size_t)e * RW + sub * 64 + lc * 8, A + s * 512 + lane * 8);
    }
    const ushort_t* wb = Wp + (size_t)vk * 8 * COfull * 8;
#pragma unroll
    for (int i = 0; i < BSEG_PW; ++i) {
      const int s = wv * BSEG_PW + i;
      int lc, co;
      if (CT == 128) { lc = s >> 1; co = (s & 1) * 64 + lane; }
      else           { lc = s;      co = lane; }
      glds16(wb + ((size_t)lc * COfull + colbase + co) * 8,
             B + s * 512 + lane * 8);
    }
  };
  auto compute = [&](const ushort_t* A, const ushort_t* B) {
    const int r0 = wm * 64 + (lane & 31);
    const int h = lane >> 5;
    const int co = wn * 32 + (lane & 31);
#pragma unroll
    for (int kc = 0; kc < 4; ++kc) {
      const int lc = kc * 2 + h;
      const int pc = lc ^ (r0 & 7);
      sh8 a0 = *(const sh8*)(A + r0 * 64 + pc * 8);
      sh8 a1 = *(const sh8*)(A + (r0 + 32) * 64 + pc * 8);
      sh8 b = *(const sh8*)(B + ((size_t)lc * CT + co) * 8);
      acc0 = __builtin_amdgcn_mfma_f32_32x32x16_bf16(a0, b, acc0, 0, 0, 0);
      acc1 = __builtin_amdgcn_mfma_f32_32x32x16_bf16(a1, b, acc1, 0, 0, 0);
    }
  };

  constexpr int NWAIT = (ASEG_PW + BSEG_PW) + (HASELL ? ASEG_PW : 0);

  int eE[ASEG_PW] = {}, eO[ASEG_PW] = {};
  loadEll(i0, eE);
  stage(i0, Ab[0], Bb[0], eE);
  if (cnt > 1) loadEll(i0 + 1, eO);

#define CONV_ITER(J, P, SE, SO)                                                \
  if ((J) < cnt) {                                                             \
    __builtin_amdgcn_sched_barrier(0); /* pin compute(J-1) above */            \
    asm volatile("s_waitcnt lgkmcnt(0)" ::: "memory");                         \
    __builtin_amdgcn_s_barrier(); /* compute(J-1) done: bufs P^1 free */       \
    if ((J) + 1 < cnt) {                                                       \
      stage(i0 + (J) + 1, Ab[(P) ^ 1], Bb[(P) ^ 1], SO);                       \
      if ((J) + 2 < cnt) loadEll(i0 + (J) + 2, SE);                            \
      if constexpr (NWAIT == 4)                                                \
        asm volatile("s_waitcnt vmcnt(4)" ::: "memory");                       \
      else if constexpr (NWAIT == 6)                                           \
        asm volatile("s_waitcnt vmcnt(6)" ::: "memory");                       \
      else                                                                     \
        asm volatile("s_waitcnt vmcnt(10)" ::: "memory");                      \
    } else {                                                                   \
      asm volatile("s_waitcnt vmcnt(0)" ::: "memory");                         \
    }                                                                          \
    __builtin_amdgcn_s_barrier(); /* stage(J) visible to all waves */          \
    __builtin_amdgcn_sched_barrier(0);                                         \
    compute(Ab[P], Bb[P]);                                                     \
  }

  for (int j = 0; j < cnt; j += 2) {
    CONV_ITER(j, 0, eE, eO)
    CONV_ITER(j + 1, 1, eO, eE)
  }
#undef CONV_ITER

  const int ccol = colbase + wn * 32 + (lane & 31);
  const int rb = wm * 64 + (lane >> 5) * 4;
#pragma unroll
  for (int rr = 0; rr < 16; ++rr) {
    long row = m0 + rb + (rr & 3) + 8 * (rr >> 2);
    if (row < n_out) out[row * COfull + ccol] = f2bf_bits(acc0[rr]);
    long row1 = row + 32;
    if (row1 < n_out) out[row1 * COfull + ccol] = f2bf_bits(acc1[rr]);
  }
}

// ---------------------------------------------------------------------------
// BN over bf16 conv outputs: two-pass stats + fused apply (res/ReLU/outs).
// ---------------------------------------------------------------------------
template <int C>
__global__ void bn_reduce1_kernel(const ushort_t* __restrict__ x, int n,
                                  float* __restrict__ part) {
  constexpr int C4 = C / 4;
  constexpr int RL = 256 / C4;
  const int c4 = threadIdx.x % C4;
  const int rl = threadIdx.x / C4;
  float4 s = {0.f, 0.f, 0.f, 0.f}, ss = {0.f, 0.f, 0.f, 0.f};
  for (long row = (long)blockIdx.x * RL + rl; row < n;
       row += (long)gridDim.x * RL) {
    ushort4 u = *(const ushort4*)(x + row * C + c4 * 4);
    float v0 = bf2f(u.x), v1 = bf2f(u.y), v2 = bf2f(u.z), v3 = bf2f(u.w);
    s.x += v0; s.y += v1; s.z += v2; s.w += v3;
    ss.x += v0 * v0; ss.y += v1 * v1; ss.z += v2 * v2; ss.w += v3 * v3;
  }
  __shared__ float4 sh[512];
  sh[threadIdx.x] = s;
  sh[256 + threadIdx.x] = ss;
  __syncthreads();
  if (rl == 0) {
#pragma unroll
    for (int j = 1; j < RL; ++j) {
      float4 a = sh[j * C4 + c4];
      float4 b = sh[256 + j * C4 + c4];
      s.x += a.x; s.y += a.y; s.z += a.z; s.w += a.w;
      ss.x += b.x; ss.y += b.y; ss.z += b.z; ss.w += b.w;
    }
    *(float4*)(part + (size_t)blockIdx.x * 2 * C + c4 * 4) = s;
    *(float4*)(part + (size_t)blockIdx.x * 2 * C + C + c4 * 4) = ss;
  }
}

// Parallel stats reduce: grid = C blocks x 256 threads (fixed-order tree).
template <int C>
__global__ void bn_reduce2_kernel(const float* __restrict__ part, int G,
                                  float* __restrict__ stats) {
  const int c = blockIdx.x;
  const int g = threadIdx.x;
  __shared__ float sh[512];
  float s = 0.f, ss = 0.f;
  if (g < G) {
    s = part[(size_t)g * 2 * C + c];
    ss = part[(size_t)g * 2 * C + C + c];
  }
  sh[g] = s;
  sh[256 + g] = ss;
  __syncthreads();
#pragma unroll
  for (int off = 128; off > 0; off >>= 1) {
    if (g < off) {
      sh[g] += sh[g + off];
      sh[256 + g] += sh[256 + g + off];
    }
    __syncthreads();
  }
  if (g == 0) {
    stats[c] = sh[0];
    stats[C + c] = sh[256];
  }
}

// Vectorized apply: one float4-worth (4 channels) per thread per step.
template <int C, bool RELU, bool RES, bool WF32>
__global__ void bn_apply_kernel(const ushort_t* __restrict__ x,
                                const float* __restrict__ stats,
                                const float* __restrict__ gamma,
                                const float* __restrict__ beta,
                                const float* __restrict__ res,
                                long total4, float inv_n,
                                float* __restrict__ out,
                                ushort_t* __restrict__ outb, long padEnd4) {
  constexpr int C4 = C / 4;
  for (long i = (long)blockIdx.x * 256 + threadIdx.x; i < padEnd4;
       i += (long)gridDim.x * 256) {
    if (i >= total4) {
      if (outb) *(ushort4*)(outb + i * 4) = (ushort4){0, 0, 0, 0};
      continue;
    }
    const int c4 = (int)(i % C4);
    float4 sum = *(const float4*)(stats + c4 * 4);
    float4 sq = *(const float4*)(stats + C + c4 * 4);
    float4 g4 = *(const float4*)(gamma + c4 * 4);
    float4 b4 = *(const float4*)(beta + c4 * 4);
    ushort4 u = *(const ushort4*)(x + i * 4);
    float vin[4] = {bf2f(u.x), bf2f(u.y), bf2f(u.z), bf2f(u.w)};
    float4 r4 = {0.f, 0.f, 0.f, 0.f};
    if (RES) r4 = *(const float4*)(res + i * 4);
    float o[4];
#pragma unroll
    for (int j = 0; j < 4; ++j) {
      float m = ((const float*)&sum)[j] * inv_n;
      float var = ((const float*)&sq)[j] * inv_n - m * m;
      float sc = rsqrtf(var + 1e-5f) * ((const float*)&g4)[j];
      float val = (vin[j] - m) * sc + ((const float*)&b4)[j];
      if (RES) val += ((const float*)&r4)[j];
      if (RELU) val = fmaxf(val, 0.f);
      o[j] = val;
    }
    if (WF32) *(float4*)(out + i * 4) = (float4){o[0], o[1], o[2], o[3]};
    if (outb) {
      ushort4 w = {f2bf_bits(o[0]), f2bf_bits(o[1]), f2bf_bits(o[2]),
                   f2bf_bits(o[3])};
      *(ushort4*)(outb + i * 4) = w;
    }
  }
}

// ---------------------------------------------------------------------------

extern "C" void kernel_launch(void* const* d_in, const int* in_sizes, int n_in,
                              void* d_out, int out_size, void* d_ws,
                              size_t ws_size, hipStream_t stream) {
  const float* feats = (const float*)d_in[0];
  const float* W0  = (const float*)d_in[1];
  const float* g0  = (const float*)d_in[2];
  const float* b0  = (const float*)d_in[3];
  const float* Ws1 = (const float*)d_in[4];
  const float* gs1 = (const float*)d_in[5];
  const float* bs1 = (const float*)d_in[6];
  const float* Wa1 = (const float*)d_in[7];
  const float* ga1 = (const float*)d_in[8];
  const float* ba1 = (const float*)d_in[9];
  const float* Wb1 = (const float*)d_in[10];
  const float* gb1 = (const float*)d_in[11];
  const float* bb1 = (const float*)d_in[12];
  const float* Ws2 = (const float*)d_in[13];
  const float* gs2 = (const float*)d_in[14];
  const float* bs2 = (const float*)d_in[15];
  const float* Wa2 = (const float*)d_in[16];
  const float* ga2 = (const float*)d_in[17];
  const float* ba2 = (const float*)d_in[18];
  const float* Wb2 = (const float*)d_in[19];
  const float* gb2 = (const float*)d_in[20];
  const float* bb2 = (const float*)d_in[21];
  const float* Wd2 = (const float*)d_in[22];
  const float* gd2 = (const float*)d_in[23];
  const float* bd2 = (const float*)d_in[24];
  const float* Ws3 = (const float*)d_in[25];
  const float* gs3 = (const float*)d_in[26];
  const float* bs3 = (const float*)d_in[27];
  const float* Wa3 = (const float*)d_in[28];
  const float* ga3 = (const float*)d_in[29];
  const float* ba3 = (const float*)d_in[30];
  const float* Wb3 = (const float*)d_in[31];
  const float* gb3 = (const float*)d_in[32];
  const float* bb3 = (const float*)d_in[33];
  const float* Wd3 = (const float*)d_in[34];
  const float* gd3 = (const float*)d_in[35];
  const float* bd3 = (const float*)d_in[36];
  const int* im0  = (const int*)d_in[40];
  const int* om0  = (const int*)d_in[41];
  const int* ims1 = (const int*)d_in[42];
  const int* oms1 = (const int*)d_in[43];
  const int* imb1 = (const int*)d_in[44];
  const int* omb1 = (const int*)d_in[45];
  const int* ims2 = (const int*)d_in[46];
  const int* oms2 = (const int*)d_in[47];
  const int* imb2 = (const int*)d_in[48];
  const int* omb2 = (const int*)d_in[49];
  const int* ims3 = (const int*)d_in[50];
  const int* oms3 = (const int*)d_in[51];
  const int* imb3 = (const int*)d_in[52];
  const int* omb3 = (const int*)d_in[53];

  const int n0 = in_sizes[0];
  const int n1 = in_sizes[37] / 3;
  const int n2 = in_sizes[38] / 3;
  const int n3 = in_sizes[39] / 3;
  const int P0  = in_sizes[40] / 125;
  const int Ps1 = in_sizes[42] / 8;
  const int Pb1 = in_sizes[44] / 27;
  const int Ps2 = in_sizes[46] / 8;
  const int Pb2 = in_sizes[48] / 27;
  const int Ps3 = in_sizes[50] / 8;
  const int Pb3 = in_sizes[52] / 27;

  // ---- workspace carve ----
  char* w = (char*)d_ws;
  auto carve = [&](size_t bytes) {
    char* p = w;
    w += (bytes + 255) & ~(size_t)255;
    return p;
  };
  int* ellS = (int*)carve((size_t)n0 * 128 * sizeof(int));
  int* ellB = (int*)carve((size_t)n1 * 28 * sizeof(int));
  float* part = (float*)carve((size_t)256 * 512 * sizeof(float));
  float* stats = (float*)carve((size_t)512 * sizeof(float));
  size_t capE = (size_t)n0 * 64 + 512;  // + pad row
  float* buf1 = (float*)carve(capE * sizeof(float));        // residual f32
  float* buf2 = (float*)carve(capE * sizeof(float));        // residual f32
  __hip_bfloat16* bbA = (__hip_bfloat16*)carve(capE * 2);   // BN bf16 outs
  __hip_bfloat16* bbB = (__hip_bfloat16*)carve(capE * 2);
  __hip_bfloat16* bbC = (__hip_bfloat16*)carve(capE * 2);
  ushort_t* cb1 = (ushort_t*)carve(capE * 2);               // conv bf16 outs
  ushort_t* cb2 = (ushort_t*)carve(capE * 2);
  ushort_t* cb3 = (ushort_t*)carve(capE * 2);
  __hip_bfloat16* xfeat = (__hip_bfloat16*)carve(((size_t)n0 + 1) * 2);

  // ---- batched weight packing (1 dispatch for all 11) ----
  PackAll pa;
  long cum = 0;
  auto addPack = [&](int idx, const float* W, int K, int cin, int cout) {
    int csplit = cin / 64;
    long elems = (long)K * csplit * 64 * cout;
    ushort_t* Wp = (ushort_t*)carve((size_t)elems * 2);
    pa.d[idx] = {W, Wp, K, csplit, cout, 0};
    pa.cum[idx] = cum;
    cum += elems;
    return Wp;
  };
  ushort_t* Ps1p = addPack(0, Ws1, 8, 64, 64);
  ushort_t* Pa1p = addPack(1, Wa1, 27, 64, 64);
  ushort_t* Pb1p = addPack(2, Wb1, 27, 64, 64);
  ushort_t* Ps2p = addPack(3, Ws2, 8, 64, 64);
  ushort_t* Pd2p = addPack(4, Wd2, 1, 64, 128);
  ushort_t* Pa2p = addPack(5, Wa2, 27, 64, 128);
  ushort_t* Pb2p = addPack(6, Wb2, 27, 128, 128);
  ushort_t* Ps3p = addPack(7, Ws3, 8, 128, 128);
  ushort_t* Pd3p = addPack(8, Wd3, 1, 128, 256);
  ushort_t* Pa3p = addPack(9, Wa3, 27, 128, 256);
  ushort_t* Pb3p = addPack(10, Wb3, 27, 256, 256);
  pa.cum[11] = cum;
  __hip_bfloat16* Wp0 = (__hip_bfloat16*)carve((size_t)128 * 64 * 2);

  pack_all_kernel<<<(int)((cum + 255) / 256), 256, 0, stream>>>(pa, cum);
  pack_w0_kernel<<<32, 256, 0, stream>>>(W0, Wp0);

  // split-K partial buffer (bf16): all remaining workspace
  size_t used = (size_t)(w - (char*)d_ws);
  ushort_t* pbufU = (ushort_t*)w;
  size_t pcapU = (ws_size > used) ? (ws_size - used) / 2 : 0;

  f2bf_kernel<<<(int)((n0 + 256) / 256), 256, 0, stream>>>(feats, xfeat, n0,
                                                           n0 + 1);

  // per-level dual ELL build: 2 dispatches per level (was 4)
  auto buildLevel = [&](const int* ims, const int* oms, int Ps, int nin_s,
                        int nout_s, const int* imb, const int* omb, int Pb,
                        int n_b) {
    long sz1 = (long)nout_s * 8, sz2 = (long)n_b * 28;
    init_ell2_kernel<<<(int)((sz1 + sz2 + 255) / 256), 256, 0, stream>>>(
        ellS, sz1, ellB, sz2);
    long t = (long)8 * Ps + (long)27 * Pb;
    build_ell2_kernel<<<(int)((t + 255) / 256), 256, 0, stream>>>(
        ims, oms, 8, 8, Ps, nin_s, nout_s, ellS,
        imb, omb, 27, 28, Pb, n_b, n_b, ellB);
  };

  // returns true if BN stats were fused into reduce_parts (split-K path)
  auto convu = [&](const void* xb, const ushort_t* Wp, const int* ellp, int S,
                   int K, int kdense, int nout, int nin, int cin, int cout,
                   ushort_t* outc) -> bool {
    int csplit = cin / 64;
    int KIv = K * csplit;
    int CT = (cout >= 128) ? 128 : 64;   // round-13 policy
    int cs = cout / CT;
    int mb = (nout + 127) / 128;
    int tiles = mb * cs;
    int ks = 1;
    if (tiles < 512 && KIv > 1) {
      ks = (512 + tiles - 1) / tiles;
      if (ks > 8) ks = 8;
      if (ks > KIv) ks = KIv;
      size_t need = (size_t)nout * cout;
      int fit = need ? (int)(pcapU / need) : 1;
      if (ks > fit) ks = fit;
      if (ks < 1) ks = 1;
    }
    int KP = (KIv + ks - 1) / ks;
    int ksE = (KIv + KP - 1) / KP;
    ushort_t* tgt = (ksE > 1) ? pbufU : outc;
    int gridx = mb * ksE * cs;
#define CU_CASE(CSV, CTV)                                                      \
  else if (csplit == CSV && CT == CTV) {                                       \
    if (ellp)                                                                  \
      conv_u_kernel<CSV, CTV, true><<<gridx, CTV * 4, 0, stream>>>(            \
          (const ushort_t*)xb, Wp, ellp, S, KIv, KP, kdense, nout, nin, cout,  \
          mb, ksE, cs, tgt);                                                   \
    else                                                                       \
      conv_u_kernel<CSV, CTV, false><<<gridx, CTV * 4, 0, stream>>>(           \
          (const ushort_t*)xb, Wp, ellp, S, KIv, KP, kdense, nout, nin, cout,  \
          mb, ksE, cs, tgt);                                                   \
  }
    if (false) {}
    CU_CASE(1, 64)
    CU_CASE(1, 128)
    CU_CASE(2, 128)
    CU_CASE(4, 128)
#undef CU_CASE
    if (ksE > 1) {
      if (cout == 64)
        reduce_parts_stats_kernel<64><<<256, 256, 0, stream>>>(pbufU, ksE,
                                                               nout, outc,
                                                               part);
      else if (cout == 128)
        reduce_parts_stats_kernel<128><<<256, 256, 0, stream>>>(pbufU, ksE,
                                                                nout, outc,
                                                                part);
      else
        reduce_parts_stats_kernel<256><<<256, 256, 0, stream>>>(pbufU, ksE,
                                                                nout, outc,
                                                                part);
      return true;
    }
    return false;
  };

  auto bn = [&](const ushort_t* x, int n, int C, const float* gamma,
                const float* beta, const float* res, bool relu, float* outp,
                __hip_bfloat16* outb, bool haveStats) {
    const int G = 256;
    float invn = 1.0f / (float)n;
    long total4 = (long)n * C / 4;
    long padEnd4 = outb ? (total4 + C / 4) : total4;
    int agrid = (int)((padEnd4 + 255) / 256);
    if (agrid > 2048) agrid = 2048;
    ushort_t* outbu = (ushort_t*)outb;
#define BN_CASE(CC)                                                            \
  else if (C == CC) {                                                          \
    if (!haveStats)                                                            \
      bn_reduce1_kernel<CC><<<G, 256, 0, stream>>>(x, n, part);                \
    bn_reduce2_kernel<CC><<<CC, 256, 0, stream>>>(part, G, stats);             \
    if (res && relu)                                                           \
      bn_apply_kernel<CC, true, true, true><<<agrid, 256, 0, stream>>>(        \
          x, stats, gamma, beta, res, total4, invn, outp, outbu, padEnd4);     \
    else if (relu && outp)                                                     \
      bn_apply_kernel<CC, true, false, true><<<agrid, 256, 0, stream>>>(       \
          x, stats, gamma, beta, nullptr, total4, invn, outp, outbu,           \
          padEnd4);                                                            \
    else if (relu)                                                             \
      bn_apply_kernel<CC, true, false, false><<<agrid, 256, 0, stream>>>(      \
          x, stats, gamma, beta, nullptr, total4, invn, nullptr, outbu,        \
          padEnd4);                                                            \
    else                                                                       \
      bn_apply_kernel<CC, false, false, true><<<agrid, 256, 0, stream>>>(      \
          x, stats, gamma, beta, nullptr, total4, invn, outp, outbu,           \
          padEnd4);                                                            \
  }
    if (false) {}
    BN_CASE(64)
    BN_CASE(128)
    BN_CASE(256)
#undef BN_CASE
  };

  float* y1 = (float*)d_out;
  float* y2 = y1 + (size_t)n1 * 64;
  float* y3 = y2 + (size_t)n2 * 128;

  // ---- stem: conv0 (k=125 -> GEMM over K=128, bf16 out) + BN ----
  {
    hipMemsetAsync(ellS, 0xFF, (size_t)n0 * 128 * sizeof(int), stream);
    int tot = 125 * P0;
    build_ell_kernel<<<(tot + 255) / 256, 256, 0, stream>>>(im0, om0, 125, 128,
                                                            P0, n0, n0, ellS);
    conv0_mfma_kernel<<<(n0 + 63) / 64, 256, 0, stream>>>(
        (const ushort_t*)xfeat, (const ushort_t*)Wp0, ellS, n0, cb1);
  }
  bn(cb1, n0, 64, g0, b0, nullptr, true, nullptr, bbA, false);      // x0

  // ---- level 1 ----
  buildLevel(ims1, oms1, Ps1, n0, n1, imb1, omb1, Pb1, n1);
  bool st;
  st = convu(bbA, Ps1p, ellS, 8, 8, 0, n1, n0, 64, 64, cb2);
  bn(cb2, n1, 64, gs1, bs1, nullptr, true, buf2, bbB, st);          // x1
  st = convu(bbB, Pa1p, ellB, 28, 27, 0, n1, n1, 64, 64, cb3);
  bn(cb3, n1, 64, ga1, ba1, nullptr, true, nullptr, bbC, st);       // h1a
  st = convu(bbC, Pb1p, ellB, 28, 27, 0, n1, n1, 64, 64, cb1);
  bn(cb1, n1, 64, gb1, bb1, buf2, true, y1, bbA, st);               // y1

  // ---- level 2 ----
  buildLevel(ims2, oms2, Ps2, n1, n2, imb2, omb2, Pb2, n2);
  st = convu(bbA, Ps2p, ellS, 8, 8, 0, n2, n1, 64, 64, cb2);
  bn(cb2, n2, 64, gs2, bs2, nullptr, true, nullptr, bbB, st);       // x2
  st = convu(bbB, Pd2p, nullptr, 1, 1, 1, n2, n2, 64, 128, cb3);
  bn(cb3, n2, 128, gd2, bd2, nullptr, false, buf1, nullptr, st);    // res2
  st = convu(bbB, Pa2p, ellB, 28, 27, 0, n2, n2, 64, 128, cb2);
  bn(cb2, n2, 128, ga2, ba2, nullptr, true, nullptr, bbC, st);      // h2a
  st = convu(bbC, Pb2p, ellB, 28, 27, 0, n2, n2, 128, 128, cb3);
  bn(cb3, n2, 128, gb2, bb2, buf1, true, y2, bbA, st);              // y2

  // ---- level 3 ----
  buildLevel(ims3, oms3, Ps3, n2, n3, imb3, omb3, Pb3, n3);
  st = convu(bbA, Ps3p, ellS, 8, 8, 0, n3, n2, 128, 128, cb1);
  bn(cb1, n3, 128, gs3, bs3, nullptr, true, nullptr, bbB, st);      // x3
  st = convu(bbB, Pd3p, nullptr, 1, 1, 1, n3, n3, 128, 256, cb2);
  bn(cb2, n3, 256, gd3, bd3, nullptr, false, buf2, nullptr, st);    // res3
  st = convu(bbB, Pa3p, ellB, 28, 27, 0, n3, n3, 128, 256, cb1);
  bn(cb1, n3, 256, ga3, ba3, nullptr, true, nullptr, bbC, st);      // h3a
  st = convu(bbC, Pb3p, ellB, 28, 27, 0, n3, n3, 256, 256, cb2);
  bn(cb2, n3, 256, gb3, bb3, buf2, true, y3, nullptr, st);          // y3
}

// Round 22
// 598.623 us; speedup vs baseline: 1.0322x; 1.0020x over previous
//
#include <hip/hip_runtime.h>
#include <hip/hip_bf16.h>
#include <cstdint>
#include <cstddef>

typedef __attribute__((ext_vector_type(8))) short sh8;
typedef __attribute__((ext_vector_type(4))) short sh4;
typedef __attribute__((ext_vector_type(4))) int ix4;
typedef __attribute__((ext_vector_type(16))) float floatx16;
typedef unsigned short ushort_t;

__device__ __forceinline__ void glds16(const ushort_t* g, ushort_t* l) {
  __builtin_amdgcn_global_load_lds(
      (const __attribute__((address_space(1))) void*)g,
      (__attribute__((address_space(3))) void*)l, 16, 0, 0);
}

__device__ __forceinline__ ushort_t f2bf_bits(float f) {
  __hip_bfloat16 b = __float2bfloat16(f);
  return __builtin_bit_cast(unsigned short, b);
}
__device__ __forceinline__ float bf2f(ushort_t u) {
  unsigned int x = ((unsigned int)u) << 16;
  return __builtin_bit_cast(float, x);
}

// ---------------------------------------------------------------------------
// ELL init/build. ell[out*S + k] = in (slot unique per (out,k) -> no atomics)
// Dual-table variants cover a whole level in 2 dispatches.
// ---------------------------------------------------------------------------
__global__ void init_ell2_kernel(int* __restrict__ e1, long sz1,
                                 int* __restrict__ e2, long sz2) {
  long i = (long)blockIdx.x * 256 + threadIdx.x;
  if (i < sz1) e1[i] = -1;
  else if (i < sz1 + sz2) e2[i - sz1] = -1;
}

__global__ void build_ell2_kernel(
    const int* __restrict__ i1, const int* __restrict__ o1, int K1, int S1,
    int P1, int nin1, int nout1, int* __restrict__ e1,
    const int* __restrict__ i2, const int* __restrict__ o2, int K2, int S2,
    int P2, int nin2, int nout2, int* __restrict__ e2) {
  long i = (long)blockIdx.x * 256 + threadIdx.x;
  long t1 = (long)K1 * P1;
  if (i < t1) {
    int vin = i1[i], vout = o1[i];
    if (vin < nin1 && vout < nout1) e1[(size_t)vout * S1 + (i / P1)] = vin;
  } else if (i < t1 + (long)K2 * P2) {
    long j = i - t1;
    int vin = i2[j], vout = o2[j];
    if (vin < nin2 && vout < nout2) e2[(size_t)vout * S2 + (j / P2)] = vin;
  }
}

__global__ void build_ell_kernel(const int* __restrict__ in_idx,
                                 const int* __restrict__ out_idx,
                                 int K, int S, int P, int n_in, int n_out,
                                 int* __restrict__ ell) {
  int i = blockIdx.x * 256 + threadIdx.x;
  if (i >= K * P) return;
  int vin = in_idx[i];
  int vout = out_idx[i];
  if (vin < n_in && vout < n_out) {
    ell[(size_t)vout * S + (i / P)] = vin;
  }
}

// ---------------------------------------------------------------------------
// Batched weight pack: 11 weights in ONE dispatch.
// Layout per weight: Wp[vk][lc 0..7][co][8] bf16 (vk = K*CSPLIT virtual iters)
// ---------------------------------------------------------------------------
struct PackDesc {
  const float* W;
  ushort_t* Wp;
  int K, CSPLIT, COUT, pad;
};
struct PackAll {
  PackDesc d[11];
  long cum[12];
};

__global__ void pack_all_kernel(PackAll pa, long grand) {
  long i = (long)blockIdx.x * 256 + threadIdx.x;
  if (i >= grand) return;
  int di = 0;
#pragma unroll
  for (int s = 0; s < 11; ++s)
    if (i >= pa.cum[s + 1]) di = s + 1;
  const PackDesc& D = pa.d[di];
  long j = i - pa.cum[di];
  int co = (int)(j % D.COUT);
  long t = j / D.COUT;
  int vch = (int)(t % 64);
  int vk = (int)(t / 64);
  int k = vk / D.CSPLIT;
  int ci = (vk % D.CSPLIT) * 64 + vch;
  int CIN = D.CSPLIT * 64;
  float v = (k < D.K) ? D.W[((long)k * CIN + ci) * D.COUT + co] : 0.f;
  D.Wp[(((long)vk * 8 + (vch >> 3)) * D.COUT + co) * 8 + (vch & 7)] =
      f2bf_bits(v);
}

// conv0 weights: W0[125][1][64] -> Wp0[k/16][co][k%16], k padded to 128.
__global__ void pack_w0_kernel(const float* __restrict__ W,
                               __hip_bfloat16* __restrict__ Wp) {
  int i = blockIdx.x * 256 + threadIdx.x;
  if (i >= 128 * 64) return;
  int co = i & 63;
  int ki = i >> 6;
  float v = (ki < 125) ? W[ki * 64 + co] : 0.f;
  Wp[(((ki >> 4) * 64) + co) * 16 + (ki & 15)] = __float2bfloat16(v);
}

// feats f32 -> bf16 with one zero pad element at the end.
__global__ void f2bf_kernel(const float* __restrict__ x,
                            __hip_bfloat16* __restrict__ y, long n, long npad) {
  long i = (long)blockIdx.x * 256 + threadIdx.x;
  if (i >= npad) return;
  y[i] = __float2bfloat16(i < n ? x[i] : 0.f);
}

// Plain fixed-order reduce (kept for completeness; unused when stats fused).
__global__ void reduce_parts_kernel(const ushort_t* __restrict__ part, int P,
                                    long total, ushort_t* __restrict__ out) {
  long i = (long)blockIdx.x * 256 + threadIdx.x;
  if (i >= total) return;
  float s = 0.f;
  for (int p = 0; p < P; ++p) s += bf2f(part[(size_t)p * total + i]);
  out[i] = f2bf_bits(s);
}

// ---------------------------------------------------------------------------
// Fixed-order sum of P bf16 partials -> bf16 final + per-block BN-stat
// partials of the ROUNDED finals. Same 256-block / RL / loop order as
// bn_reduce1 -> stats are bit-identical to the two-pass version.
// ---------------------------------------------------------------------------
template <int C>
__global__ void reduce_parts_stats_kernel(const ushort_t* __restrict__ pin,
                                          int P, int n,
                                          ushort_t* __restrict__ out,
                                          float* __restrict__ part) {
  constexpr int C4 = C / 4;
  constexpr int RL = 256 / C4;
  const long total = (long)n * C;
  const int c4 = threadIdx.x % C4;
  const int rl = threadIdx.x / C4;
  float4 s = {0.f, 0.f, 0.f, 0.f}, ss = {0.f, 0.f, 0.f, 0.f};
  for (long row = (long)blockIdx.x * RL + rl; row < n;
       row += (long)gridDim.x * RL) {
    long base = row * C + c4 * 4;
    float f0 = 0.f, f1 = 0.f, f2 = 0.f, f3 = 0.f;
    for (int p = 0; p < P; ++p) {
      ushort4 u = *(const ushort4*)(pin + (size_t)p * total + base);
      f0 += bf2f(u.x); f1 += bf2f(u.y); f2 += bf2f(u.z); f3 += bf2f(u.w);
    }
    ushort4 w = {f2bf_bits(f0), f2bf_bits(f1), f2bf_bits(f2), f2bf_bits(f3)};
    *(ushort4*)(out + base) = w;
    float v0 = bf2f(w.x), v1 = bf2f(w.y), v2 = bf2f(w.z), v3 = bf2f(w.w);
    s.x += v0; s.y += v1; s.z += v2; s.w += v3;
    ss.x += v0 * v0; ss.y += v1 * v1; ss.z += v2 * v2; ss.w += v3 * v3;
  }
  __shared__ float4 sh[512];
  sh[threadIdx.x] = s;
  sh[256 + threadIdx.x] = ss;
  __syncthreads();
  if (rl == 0) {
#pragma unroll
    for (int j = 1; j < RL; ++j) {
      float4 a = sh[j * C4 + c4];
      float4 b = sh[256 + j * C4 + c4];
      s.x += a.x; s.y += a.y; s.z += a.z; s.w += a.w;
      ss.x += b.x; ss.y += b.y; ss.z += b.z; ss.w += b.w;
    }
    *(float4*)(part + (size_t)blockIdx.x * 2 * C + c4 * 4) = s;
    *(float4*)(part + (size_t)blockIdx.x * 2 * C + C + c4 * 4) = ss;
  }
}

// ---------------------------------------------------------------------------
// conv0: out[n0][64] (bf16) = gatherA(x1ch, ell[*,128]) @ W0, 32x32x16 MFMA.
// ---------------------------------------------------------------------------
__global__ __launch_bounds__(256, 2) void conv0_mfma_kernel(
    const ushort_t* __restrict__ xpad, const ushort_t* __restrict__ Wp0,
    const int* __restrict__ ell, int n_out, ushort_t* __restrict__ out) {
  constexpr int STR = 152;
  __shared__ ushort_t xs[64 * STR];
  const int tid = threadIdx.x;
  const int lane = tid & 63;
  const int wv = tid >> 6;
  const int wm = wv & 1, wn = wv >> 1;
  const long m0 = (long)blockIdx.x * 64;
  const int row = tid >> 2;
  const int kk0 = (tid & 3) * 32;
  const long grow = m0 + row;

  if (grow < n_out) {
    const ix4* ep = (const ix4*)(ell + grow * 128 + kk0);
#pragma unroll
    for (int g = 0; g < 8; ++g) {
      ix4 e = ep[g];
      sh4 v;
#pragma unroll
      for (int j = 0; j < 4; ++j) {
        int ix = (e[j] < 0) ? n_out : e[j];
        v[j] = (short)xpad[ix];
      }
      *(sh4*)(&xs[row * STR + kk0 + g * 4]) = v;
    }
  } else {
    sh4 z = (sh4)(short)0;
#pragma unroll
    for (int g = 0; g < 8; ++g) *(sh4*)(&xs[row * STR + kk0 + g * 4]) = z;
  }
  __syncthreads();

  const int arow = wm * 32 + (lane & 31);
  const int koff = (lane >> 5) * 8;
  const int bcol = wn * 32 + (lane & 31);
  floatx16 acc = (floatx16)(0.0f);
#pragma unroll
  for (int kc = 0; kc < 8; ++kc) {
    sh8 a = *(const sh8*)(&xs[arow * STR + kc * 16 + koff]);
    sh8 b = *(const sh8*)(Wp0 + ((size_t)kc * 64 + bcol) * 16 + koff);
    acc = __builtin_amdgcn_mfma_f32_32x32x16_bf16(a, b, acc, 0, 0, 0);
  }
  const int lrow = (lane >> 5) * 4;
#pragma unroll
  for (int r = 0; r < 16; ++r) {
    long orow = m0 + wm * 32 + (r & 3) + 8 * (r >> 2) + lrow;
    if (orow < n_out) out[orow * 64 + bcol] = f2bf_bits(acc[r]);
  }
}

// ---------------------------------------------------------------------------
// Unified MFMA implicit-GEMM conv, BM=128 x CT (128 for COUT>=128, else 64).
// BOTH A and B double-buffered (empirically the ONLY race-free schedule:
// dual-B 3/3 pass, single-B 1/4). Counted-vmcnt pipeline, 2 raw barriers/iter
// with lgkmcnt(0)+sched_barrier hardening before the WAR-side barrier.
// 1D grid + bijective chunked XCD swizzle; raw ell register-prefetch.
// Output always bf16 (finals or split-K partials at +yk*n*CO).
// LDS: CT=128 -> 64KB (2 blocks/CU); CT=64 -> 48KB (3 blocks/CU).
// ---------------------------------------------------------------------------
template <int CSPLIT, int CT, bool HASELL>
__global__ __launch_bounds__(CT * 4, CT == 128 ? 4 : 3) void conv_u_kernel(
    const ushort_t* __restrict__ xb, const ushort_t* __restrict__ Wp,
    const int* __restrict__ ell, int S, int KI, int KP, int kdense,
    int n_out, int n_in, int COfull, int MB, int KS, int CS,
    ushort_t* __restrict__ out) {
  constexpr int BLK = CT * 4;
  constexpr int NWN = CT / 32;
  constexpr int ASEG_PW = 16 / (BLK / 64);        // 2 (CT=128) or 4 (CT=64)
  constexpr int BSEG_PW = (CT / 8) / (BLK / 64);  // 2
  constexpr int RW = CSPLIT * 64;
  __shared__ ushort_t Ab[2][128 * 64];
  __shared__ ushort_t Bb[2][8 * CT * 8];
  const int tid = threadIdx.x;
  const int lane = tid & 63;
  const int wv = tid >> 6;
  const int wm = wv / NWN, wn = wv % NWN;

  const int total = MB * KS * CS;
  const int l = blockIdx.x;
  const int q = total >> 3, r8 = total & 7;
  const int xcd = l & 7, pos = l >> 3;
  const int lp = (xcd < r8) ? (xcd * (q + 1) + pos)
                            : (r8 * (q + 1) + (xcd - r8) * q + pos);
  const int mblk = lp / (KS * CS);
  const int rem = lp - mblk * (KS * CS);
  const int yk = rem / CS;
  const int zc = rem - yk * CS;
  const long m0 = (long)mblk * 128;
  const int colbase = zc * CT;

  const int i0 = yk * KP;
  int cnt = KI - i0;
  if (cnt > KP) cnt = KP;
  out += (size_t)yk * ((size_t)n_out * COfull);

  floatx16 acc0 = (floatx16)(0.0f);
  floatx16 acc1 = (floatx16)(0.0f);

  auto loadEll = [&](int vk, int (&e)[ASEG_PW]) {
    if constexpr (HASELL) {
      const int kq = (CSPLIT == 1) ? vk : (vk / CSPLIT);
#pragma unroll
      for (int i = 0; i < ASEG_PW; ++i) {
        const int s = wv * ASEG_PW + i;
        const int r = s * 8 + (lane >> 3);
        long grow = m0 + r;
        long gc = grow < (long)(n_out - 1) ? grow : (long)(n_out - 1);
        e[i] = ell[gc * (long)S + kq];   // raw; masked at use
      }
    }
  };

  auto stage = [&](int vk, ushort_t* A, ushort_t* B, int (&eRaw)[ASEG_PW]) {
    const int sub = (CSPLIT == 1) ? 0 : (vk % CSPLIT);
    const int kq = (CSPLIT == 1) ? vk : (vk / CSPLIT);
#pragma unroll
    for (int i = 0; i < ASEG_PW; ++i) {
      const int s = wv * ASEG_PW + i;
      const int r = s * 8 + (lane >> 3);
      const long grow = m0 + r;
      int v;
      if constexpr (HASELL) v = eRaw[i];
      else v = (kq < kdense) ? (int)grow : -1;
      if (grow >= (long)n_out) v = -1;
      const int e = (v < 0) ? n_in : v;
      const int c = lane & 7;
      const int lc = c ^ (r & 7);
      glds16(xb + (size_t)e * RW + sub * 64 + lc * 8, A + s * 512 + lane * 8);
    }
    const ushort_t* wb = Wp + (size_t)vk * 8 * COfull * 8;
#pragma unroll
    for (int i = 0; i < BSEG_PW; ++i) {
      const int s = wv * BSEG_PW + i;
      int lc, co;
      if (CT == 128) { lc = s >> 1; co = (s & 1) * 64 + lane; }
      else           { lc = s;      co = lane; }
      glds16(wb + ((size_t)lc * COfull + colbase + co) * 8,
             B + s * 512 + lane * 8);
    }
  };
  auto compute = [&](const ushort_t* A, const ushort_t* B) {
    const int r0 = wm * 64 + (lane & 31);
    const int h = lane >> 5;
    const int co = wn * 32 + (lane & 31);
#pragma unroll
    for (int kc = 0; kc < 4; ++kc) {
      const int lc = kc * 2 + h;
      const int pc = lc ^ (r0 & 7);
      sh8 a0 = *(const sh8*)(A + r0 * 64 + pc * 8);
      sh8 a1 = *(const sh8*)(A + (r0 + 32) * 64 + pc * 8);
      sh8 b = *(const sh8*)(B + ((size_t)lc * CT + co) * 8);
      acc0 = __builtin_amdgcn_mfma_f32_32x32x16_bf16(a0, b, acc0, 0, 0, 0);
      acc1 = __builtin_amdgcn_mfma_f32_32x32x16_bf16(a1, b, acc1, 0, 0, 0);
    }
  };

  constexpr int NWAIT = (ASEG_PW + BSEG_PW) + (HASELL ? ASEG_PW : 0);

  int eE[ASEG_PW] = {}, eO[ASEG_PW] = {};
  loadEll(i0, eE);
  stage(i0, Ab[0], Bb[0], eE);
  if (cnt > 1) loadEll(i0 + 1, eO);

#define CONV_ITER(J, P, SE, SO)                                                \
  if ((J) < cnt) {                                                             \
    __builtin_amdgcn_sched_barrier(0); /* pin compute(J-1) above */            \
    asm volatile("s_waitcnt lgkmcnt(0)" ::: "memory");                         \
    __builtin_amdgcn_s_barrier(); /* compute(J-1) done: bufs P^1 free */       \
    if ((J) + 1 < cnt) {                                                       \
      stage(i0 + (J) + 1, Ab[(P) ^ 1], Bb[(P) ^ 1], SO);                       \
      if ((J) + 2 < cnt) loadEll(i0 + (J) + 2, SE);                            \
      if constexpr (NWAIT == 4)                                                \
        asm volatile("s_waitcnt vmcnt(4)" ::: "memory");                       \
      else if constexpr (NWAIT == 6)                                           \
        asm volatile("s_waitcnt vmcnt(6)" ::: "memory");                       \
      else                                                                     \
        asm volatile("s_waitcnt vmcnt(10)" ::: "memory");                      \
    } else {                                                                   \
      asm volatile("s_waitcnt vmcnt(0)" ::: "memory");                         \
    }                                                                          \
    __builtin_amdgcn_s_barrier(); /* stage(J) visible to all waves */          \
    __builtin_amdgcn_sched_barrier(0);                                         \
    compute(Ab[P], Bb[P]);                                                     \
  }

  for (int j = 0; j < cnt; j += 2) {
    CONV_ITER(j, 0, eE, eO)
    CONV_ITER(j + 1, 1, eO, eE)
  }
#undef CONV_ITER

  const int ccol = colbase + wn * 32 + (lane & 31);
  const int rb = wm * 64 + (lane >> 5) * 4;
#pragma unroll
  for (int rr = 0; rr < 16; ++rr) {
    long row = m0 + rb + (rr & 3) + 8 * (rr >> 2);
    if (row < n_out) out[row * COfull + ccol] = f2bf_bits(acc0[rr]);
    long row1 = row + 32;
    if (row1 < n_out) out[row1 * COfull + ccol] = f2bf_bits(acc1[rr]);
  }
}

// ---------------------------------------------------------------------------
// BN over bf16 conv outputs: two-pass stats + fused apply (res/ReLU/outs).
// ---------------------------------------------------------------------------
template <int C>
__global__ void bn_reduce1_kernel(const ushort_t* __restrict__ x, int n,
                                  float* __restrict__ part) {
  constexpr int C4 = C / 4;
  constexpr int RL = 256 / C4;
  const int c4 = threadIdx.x % C4;
  const int rl = threadIdx.x / C4;
  float4 s = {0.f, 0.f, 0.f, 0.f}, ss = {0.f, 0.f, 0.f, 0.f};
  for (long row = (long)blockIdx.x * RL + rl; row < n;
       row += (long)gridDim.x * RL) {
    ushort4 u = *(const ushort4*)(x + row * C + c4 * 4);
    float v0 = bf2f(u.x), v1 = bf2f(u.y), v2 = bf2f(u.z), v3 = bf2f(u.w);
    s.x += v0; s.y += v1; s.z += v2; s.w += v3;
    ss.x += v0 * v0; ss.y += v1 * v1; ss.z += v2 * v2; ss.w += v3 * v3;
  }
  __shared__ float4 sh[512];
  sh[threadIdx.x] = s;
  sh[256 + threadIdx.x] = ss;
  __syncthreads();
  if (rl == 0) {
#pragma unroll
    for (int j = 1; j < RL; ++j) {
      float4 a = sh[j * C4 + c4];
      float4 b = sh[256 + j * C4 + c4];
      s.x += a.x; s.y += a.y; s.z += a.z; s.w += a.w;
      ss.x += b.x; ss.y += b.y; ss.z += b.z; ss.w += b.w;
    }
    *(float4*)(part + (size_t)blockIdx.x * 2 * C + c4 * 4) = s;
    *(float4*)(part + (size_t)blockIdx.x * 2 * C + C + c4 * 4) = ss;
  }
}

// Parallel stats reduce: grid = C blocks x 256 threads (fixed-order tree).
template <int C>
__global__ void bn_reduce2_kernel(const float* __restrict__ part, int G,
                                  float* __restrict__ stats) {
  const int c = blockIdx.x;
  const int g = threadIdx.x;
  __shared__ float sh[512];
  float s = 0.f, ss = 0.f;
  if (g < G) {
    s = part[(size_t)g * 2 * C + c];
    ss = part[(size_t)g * 2 * C + C + c];
  }
  sh[g] = s;
  sh[256 + g] = ss;
  __syncthreads();
#pragma unroll
  for (int off = 128; off > 0; off >>= 1) {
    if (g < off) {
      sh[g] += sh[g + off];
      sh[256 + g] += sh[256 + g + off];
    }
    __syncthreads();
  }
  if (g == 0) {
    stats[c] = sh[0];
    stats[C + c] = sh[256];
  }
}

// Vectorized apply: one float4-worth (4 channels) per thread per step.
template <int C, bool RELU, bool RES, bool WF32>
__global__ void bn_apply_kernel(const ushort_t* __restrict__ x,
                                const float* __restrict__ stats,
                                const float* __restrict__ gamma,
                                const float* __restrict__ beta,
                                const float* __restrict__ res,
                                long total4, float inv_n,
                                float* __restrict__ out,
                                ushort_t* __restrict__ outb, long padEnd4) {
  constexpr int C4 = C / 4;
  for (long i = (long)blockIdx.x * 256 + threadIdx.x; i < padEnd4;
       i += (long)gridDim.x * 256) {
    if (i >= total4) {
      if (outb) *(ushort4*)(outb + i * 4) = (ushort4){0, 0, 0, 0};
      continue;
    }
    const int c4 = (int)(i % C4);
    float4 sum = *(const float4*)(stats + c4 * 4);
    float4 sq = *(const float4*)(stats + C + c4 * 4);
    float4 g4 = *(const float4*)(gamma + c4 * 4);
    float4 b4 = *(const float4*)(beta + c4 * 4);
    ushort4 u = *(const ushort4*)(x + i * 4);
    float vin[4] = {bf2f(u.x), bf2f(u.y), bf2f(u.z), bf2f(u.w)};
    float4 r4 = {0.f, 0.f, 0.f, 0.f};
    if (RES) r4 = *(const float4*)(res + i * 4);
    float o[4];
#pragma unroll
    for (int j = 0; j < 4; ++j) {
      float m = ((const float*)&sum)[j] * inv_n;
      float var = ((const float*)&sq)[j] * inv_n - m * m;
      float sc = rsqrtf(var + 1e-5f) * ((const float*)&g4)[j];
      float val = (vin[j] - m) * sc + ((const float*)&b4)[j];
      if (RES) val += ((const float*)&r4)[j];
      if (RELU) val = fmaxf(val, 0.f);
      o[j] = val;
    }
    if (WF32) *(float4*)(out + i * 4) = (float4){o[0], o[1], o[2], o[3]};
    if (outb) {
      ushort4 w = {f2bf_bits(o[0]), f2bf_bits(o[1]), f2bf_bits(o[2]),
                   f2bf_bits(o[3])};
      *(ushort4*)(outb + i * 4) = w;
    }
  }
}

// ---------------------------------------------------------------------------

extern "C" void kernel_launch(void* const* d_in, const int* in_sizes, int n_in,
                              void* d_out, int out_size, void* d_ws,
                              size_t ws_size, hipStream_t stream) {
  const float* feats = (const float*)d_in[0];
  const float* W0  = (const float*)d_in[1];
  const float* g0  = (const float*)d_in[2];
  const float* b0  = (const float*)d_in[3];
  const float* Ws1 = (const float*)d_in[4];
  const float* gs1 = (const float*)d_in[5];
  const float* bs1 = (const float*)d_in[6];
  const float* Wa1 = (const float*)d_in[7];
  const float* ga1 = (const float*)d_in[8];
  const float* ba1 = (const float*)d_in[9];
  const float* Wb1 = (const float*)d_in[10];
  const float* gb1 = (const float*)d_in[11];
  const float* bb1 = (const float*)d_in[12];
  const float* Ws2 = (const float*)d_in[13];
  const float* gs2 = (const float*)d_in[14];
  const float* bs2 = (const float*)d_in[15];
  const float* Wa2 = (const float*)d_in[16];
  const float* ga2 = (const float*)d_in[17];
  const float* ba2 = (const float*)d_in[18];
  const float* Wb2 = (const float*)d_in[19];
  const float* gb2 = (const float*)d_in[20];
  const float* bb2 = (const float*)d_in[21];
  const float* Wd2 = (const float*)d_in[22];
  const float* gd2 = (const float*)d_in[23];
  const float* bd2 = (const float*)d_in[24];
  const float* Ws3 = (const float*)d_in[25];
  const float* gs3 = (const float*)d_in[26];
  const float* bs3 = (const float*)d_in[27];
  const float* Wa3 = (const float*)d_in[28];
  const float* ga3 = (const float*)d_in[29];
  const float* ba3 = (const float*)d_in[30];
  const float* Wb3 = (const float*)d_in[31];
  const float* gb3 = (const float*)d_in[32];
  const float* bb3 = (const float*)d_in[33];
  const float* Wd3 = (const float*)d_in[34];
  const float* gd3 = (const float*)d_in[35];
  const float* bd3 = (const float*)d_in[36];
  const int* im0  = (const int*)d_in[40];
  const int* om0  = (const int*)d_in[41];
  const int* ims1 = (const int*)d_in[42];
  const int* oms1 = (const int*)d_in[43];
  const int* imb1 = (const int*)d_in[44];
  const int* omb1 = (const int*)d_in[45];
  const int* ims2 = (const int*)d_in[46];
  const int* oms2 = (const int*)d_in[47];
  const int* imb2 = (const int*)d_in[48];
  const int* omb2 = (const int*)d_in[49];
  const int* ims3 = (const int*)d_in[50];
  const int* oms3 = (const int*)d_in[51];
  const int* imb3 = (const int*)d_in[52];
  const int* omb3 = (const int*)d_in[53];

  const int n0 = in_sizes[0];
  const int n1 = in_sizes[37] / 3;
  const int n2 = in_sizes[38] / 3;
  const int n3 = in_sizes[39] / 3;
  const int P0  = in_sizes[40] / 125;
  const int Ps1 = in_sizes[42] / 8;
  const int Pb1 = in_sizes[44] / 27;
  const int Ps2 = in_sizes[46] / 8;
  const int Pb2 = in_sizes[48] / 27;
  const int Ps3 = in_sizes[50] / 8;
  const int Pb3 = in_sizes[52] / 27;

  // ---- workspace carve ----
  char* w = (char*)d_ws;
  auto carve = [&](size_t bytes) {
    char* p = w;
    w += (bytes + 255) & ~(size_t)255;
    return p;
  };
  int* ellS = (int*)carve((size_t)n0 * 128 * sizeof(int));
  int* ellB = (int*)carve((size_t)n1 * 28 * sizeof(int));
  float* part = (float*)carve((size_t)256 * 512 * sizeof(float));
  float* stats = (float*)carve((size_t)512 * sizeof(float));
  size_t capE = (size_t)n0 * 64 + 512;  // + pad row
  float* buf1 = (float*)carve(capE * sizeof(float));        // residual f32
  float* buf2 = (float*)carve(capE * sizeof(float));        // residual f32
  __hip_bfloat16* bbA = (__hip_bfloat16*)carve(capE * 2);   // BN bf16 outs
  __hip_bfloat16* bbB = (__hip_bfloat16*)carve(capE * 2);
  __hip_bfloat16* bbC = (__hip_bfloat16*)carve(capE * 2);
  ushort_t* cb1 = (ushort_t*)carve(capE * 2);               // conv bf16 outs
  ushort_t* cb2 = (ushort_t*)carve(capE * 2);
  ushort_t* cb3 = (ushort_t*)carve(capE * 2);
  __hip_bfloat16* xfeat = (__hip_bfloat16*)carve(((size_t)n0 + 1) * 2);

  // ---- batched weight packing (1 dispatch for all 11) ----
  PackAll pa;
  long cum = 0;
  auto addPack = [&](int idx, const float* W, int K, int cin, int cout) {
    int csplit = cin / 64;
    long elems = (long)K * csplit * 64 * cout;
    ushort_t* Wp = (ushort_t*)carve((size_t)elems * 2);
    pa.d[idx] = {W, Wp, K, csplit, cout, 0};
    pa.cum[idx] = cum;
    cum += elems;
    return Wp;
  };
  ushort_t* Ps1p = addPack(0, Ws1, 8, 64, 64);
  ushort_t* Pa1p = addPack(1, Wa1, 27, 64, 64);
  ushort_t* Pb1p = addPack(2, Wb1, 27, 64, 64);
  ushort_t* Ps2p = addPack(3, Ws2, 8, 64, 64);
  ushort_t* Pd2p = addPack(4, Wd2, 1, 64, 128);
  ushort_t* Pa2p = addPack(5, Wa2, 27, 64, 128);
  ushort_t* Pb2p = addPack(6, Wb2, 27, 128, 128);
  ushort_t* Ps3p = addPack(7, Ws3, 8, 128, 128);
  ushort_t* Pd3p = addPack(8, Wd3, 1, 128, 256);
  ushort_t* Pa3p = addPack(9, Wa3, 27, 128, 256);
  ushort_t* Pb3p = addPack(10, Wb3, 27, 256, 256);
  pa.cum[11] = cum;
  __hip_bfloat16* Wp0 = (__hip_bfloat16*)carve((size_t)128 * 64 * 2);

  pack_all_kernel<<<(int)((cum + 255) / 256), 256, 0, stream>>>(pa, cum);
  pack_w0_kernel<<<32, 256, 0, stream>>>(W0, Wp0);

  // split-K partial buffer (bf16): all remaining workspace
  size_t used = (size_t)(w - (char*)d_ws);
  ushort_t* pbufU = (ushort_t*)w;
  size_t pcapU = (ws_size > used) ? (ws_size - used) / 2 : 0;

  f2bf_kernel<<<(int)((n0 + 256) / 256), 256, 0, stream>>>(feats, xfeat, n0,
                                                           n0 + 1);

  // per-level dual ELL build: 2 dispatches per level (was 4)
  auto buildLevel = [&](const int* ims, const int* oms, int Ps, int nin_s,
                        int nout_s, const int* imb, const int* omb, int Pb,
                        int n_b) {
    long sz1 = (long)nout_s * 8, sz2 = (long)n_b * 28;
    init_ell2_kernel<<<(int)((sz1 + sz2 + 255) / 256), 256, 0, stream>>>(
        ellS, sz1, ellB, sz2);
    long t = (long)8 * Ps + (long)27 * Pb;
    build_ell2_kernel<<<(int)((t + 255) / 256), 256, 0, stream>>>(
        ims, oms, 8, 8, Ps, nin_s, nout_s, ellS,
        imb, omb, 27, 28, Pb, n_b, n_b, ellB);
  };

  // returns true if BN stats were fused into reduce_parts (split-K path)
  auto convu = [&](const void* xb, const ushort_t* Wp, const int* ellp, int S,
                   int K, int kdense, int nout, int nin, int cin, int cout,
                   ushort_t* outc) -> bool {
    int csplit = cin / 64;
    int KIv = K * csplit;
    int CT = (cout >= 128) ? 128 : 64;   // round-13 policy
    int cs = cout / CT;
    int mb = (nout + 127) / 128;
    int tiles = mb * cs;
    int ks = 1;
    if (tiles < 512 && KIv > 1) {
      ks = (512 + tiles - 1) / tiles;
      if (ks > 8) ks = 8;
      if (ks > KIv) ks = KIv;
      size_t need = (size_t)nout * cout;
      int fit = need ? (int)(pcapU / need) : 1;
      if (ks > fit) ks = fit;
      if (ks < 1) ks = 1;
    }
    int KP = (KIv + ks - 1) / ks;
    int ksE = (KIv + KP - 1) / KP;
    ushort_t* tgt = (ksE > 1) ? pbufU : outc;
    int gridx = mb * ksE * cs;
#define CU_CASE(CSV, CTV)                                                      \
  else if (csplit == CSV && CT == CTV) {                                       \
    if (ellp)                                                                  \
      conv_u_kernel<CSV, CTV, true><<<gridx, CTV * 4, 0, stream>>>(            \
          (const ushort_t*)xb, Wp, ellp, S, KIv, KP, kdense, nout, nin, cout,  \
          mb, ksE, cs, tgt);                                                   \
    else                                                                       \
      conv_u_kernel<CSV, CTV, false><<<gridx, CTV * 4, 0, stream>>>(           \
          (const ushort_t*)xb, Wp, ellp, S, KIv, KP, kdense, nout, nin, cout,  \
          mb, ksE, cs, tgt);                                                   \
  }
    if (false) {}
    CU_CASE(1, 64)
    CU_CASE(1, 128)
    CU_CASE(2, 128)
    CU_CASE(4, 128)
#undef CU_CASE
    if (ksE > 1) {
      if (cout == 64)
        reduce_parts_stats_kernel<64><<<256, 256, 0, stream>>>(pbufU, ksE,
                                                               nout, outc,
                                                               part);
      else if (cout == 128)
        reduce_parts_stats_kernel<128><<<256, 256, 0, stream>>>(pbufU, ksE,
                                                                nout, outc,
                                                                part);
      else
        reduce_parts_stats_kernel<256><<<256, 256, 0, stream>>>(pbufU, ksE,
                                                                nout, outc,
                                                                part);
      return true;
    }
    return false;
  };

  auto bn = [&](const ushort_t* x, int n, int C, const float* gamma,
                const float* beta, const float* res, bool relu, float* outp,
                __hip_bfloat16* outb, bool haveStats) {
    const int G = 256;
    float invn = 1.0f / (float)n;
    long total4 = (long)n * C / 4;
    long padEnd4 = outb ? (total4 + C / 4) : total4;
    int agrid = (int)((padEnd4 + 255) / 256);
    if (agrid > 2048) agrid = 2048;
    ushort_t* outbu = (ushort_t*)outb;
#define BN_CASE(CC)                                                            \
  else if (C == CC) {                                                          \
    if (!haveStats)                                                            \
      bn_reduce1_kernel<CC><<<G, 256, 0, stream>>>(x, n, part);                \
    bn_reduce2_kernel<CC><<<CC, 256, 0, stream>>>(part, G, stats);             \
    if (res && relu)                                                           \
      bn_apply_kernel<CC, true, true, true><<<agrid, 256, 0, stream>>>(        \
          x, stats, gamma, beta, res, total4, invn, outp, outbu, padEnd4);     \
    else if (relu && outp)                                                     \
      bn_apply_kernel<CC, true, false, true><<<agrid, 256, 0, stream>>>(       \
          x, stats, gamma, beta, nullptr, total4, invn, outp, outbu,           \
          padEnd4);                                                            \
    else if (relu)                                                             \
      bn_apply_kernel<CC, true, false, false><<<agrid, 256, 0, stream>>>(      \
          x, stats, gamma, beta, nullptr, total4, invn, nullptr, outbu,        \
          padEnd4);                                                            \
    else                                                                       \
      bn_apply_kernel<CC, false, false, true><<<agrid, 256, 0, stream>>>(      \
          x, stats, gamma, beta, nullptr, total4, invn, outp, outbu,           \
          padEnd4);                                                            \
  }
    if (false) {}
    BN_CASE(64)
    BN_CASE(128)
    BN_CASE(256)
#undef BN_CASE
  };

  float* y1 = (float*)d_out;
  float* y2 = y1 + (size_t)n1 * 64;
  float* y3 = y2 + (size_t)n2 * 128;

  // ---- stem: conv0 (k=125 -> GEMM over K=128, bf16 out) + BN ----
  {
    hipMemsetAsync(ellS, 0xFF, (size_t)n0 * 128 * sizeof(int), stream);
    int tot = 125 * P0;
    build_ell_kernel<<<(tot + 255) / 256, 256, 0, stream>>>(im0, om0, 125, 128,
                                                            P0, n0, n0, ellS);
    conv0_mfma_kernel<<<(n0 + 63) / 64, 256, 0, stream>>>(
        (const ushort_t*)xfeat, (const ushort_t*)Wp0, ellS, n0, cb1);
  }
  bn(cb1, n0, 64, g0, b0, nullptr, true, nullptr, bbA, false);      // x0

  // ---- level 1 ----
  buildLevel(ims1, oms1, Ps1, n0, n1, imb1, omb1, Pb1, n1);
  bool st;
  st = convu(bbA, Ps1p, ellS, 8, 8, 0, n1, n0, 64, 64, cb2);
  bn(cb2, n1, 64, gs1, bs1, nullptr, true, buf2, bbB, st);          // x1
  st = convu(bbB, Pa1p, ellB, 28, 27, 0, n1, n1, 64, 64, cb3);
  bn(cb3, n1, 64, ga1, ba1, nullptr, true, nullptr, bbC, st);       // h1a
  st = convu(bbC, Pb1p, ellB, 28, 27, 0, n1, n1, 64, 64, cb1);
  bn(cb1, n1, 64, gb1, bb1, buf2, true, y1, bbA, st);               // y1

  // ---- level 2 ----
  buildLevel(ims2, oms2, Ps2, n1, n2, imb2, omb2, Pb2, n2);
  st = convu(bbA, Ps2p, ellS, 8, 8, 0, n2, n1, 64, 64, cb2);
  bn(cb2, n2, 64, gs2, bs2, nullptr, true, nullptr, bbB, st);       // x2
  st = convu(bbB, Pd2p, nullptr, 1, 1, 1, n2, n2, 64, 128, cb3);
  bn(cb3, n2, 128, gd2, bd2, nullptr, false, buf1, nullptr, st);    // res2
  st = convu(bbB, Pa2p, ellB, 28, 27, 0, n2, n2, 64, 128, cb2);
  bn(cb2, n2, 128, ga2, ba2, nullptr, true, nullptr, bbC, st);      // h2a
  st = convu(bbC, Pb2p, ellB, 28, 27, 0, n2, n2, 128, 128, cb3);
  bn(cb3, n2, 128, gb2, bb2, buf1, true, y2, bbA, st);              // y2

  // ---- level 3 ----
  buildLevel(ims3, oms3, Ps3, n2, n3, imb3, omb3, Pb3, n3);
  st = convu(bbA, Ps3p, ellS, 8, 8, 0, n3, n2, 128, 128, cb1);
  bn(cb1, n3, 128, gs3, bs3, nullptr, true, nullptr, bbB, st);      // x3
  st = convu(bbB, Pd3p, nullptr, 1, 1, 1, n3, n3, 128, 256, cb2);
  bn(cb2, n3, 256, gd3, bd3, nullptr, false, buf2, nullptr, st);    // res3
  st = convu(bbB, Pa3p, ellB, 28, 27, 0, n3, n3, 128, 256, cb1);
  bn(cb1, n3, 256, ga3, ba3, nullptr, true, nullptr, bbC, st);      // h3a
  st = convu(bbC, Pb3p, ellB, 28, 27, 0, n3, n3, 256, 256, cb2);
  bn(cb2, n3, 256, gb3, bb3, buf2, true, y3, nullptr, st);          // y3
}